// Round 2
// baseline (19356.375 us; speedup 1.0000x reference)
//
#include <hip/hip_runtime.h>
#include <hip/hip_bf16.h>

typedef unsigned short u16;
typedef unsigned int   u32;
typedef unsigned long long u64;
typedef __attribute__((ext_vector_type(8))) short short8;
typedef __attribute__((ext_vector_type(4))) float f32x4;

__device__ __forceinline__ float bf2f(u16 u) {
  union { u32 i; float f; } v; v.i = ((u32)u) << 16; return v.f;
}
__device__ __forceinline__ u16 f2bf(float f) {
  union { float f; u32 i; } v; v.f = f;
  return (u16)((v.i + 0x7FFFu + ((v.i >> 16) & 1u)) >> 16);
}

typedef const __attribute__((address_space(1))) u32* gas_t;
typedef __attribute__((address_space(3)))       u32* las_t;
__device__ __forceinline__ void gld16(const void* g, void* l) {
  __builtin_amdgcn_global_load_lds((gas_t)g, (las_t)l, 16, 0, 0);
}

// ---------------- elementwise prep ----------------
__global__ __launch_bounds__(256) void cast_kernel(const float* __restrict__ src,
                                                   u16* __restrict__ dst, int n) {
  int i = (blockIdx.x * 256 + threadIdx.x) * 4;
  if (i >= n) return;
  float4 v = *(const float4*)(src + i);
  uint2 o;
  o.x = (u32)f2bf(v.x) | ((u32)f2bf(v.y) << 16);
  o.y = (u32)f2bf(v.z) | ((u32)f2bf(v.w) << 16);
  *(uint2*)(dst + i) = o;
}

// dst[c][r] = bf16(src[r][c]);  R,C multiples of 32
__global__ __launch_bounds__(256) void tcast_kernel(const float* __restrict__ src,
                                                    u16* __restrict__ dst, int R, int C) {
  __shared__ u16 tile[32][33];
  int c0 = blockIdx.x * 32, r0 = blockIdx.y * 32;
  for (int dy = threadIdx.y; dy < 32; dy += 8)
    tile[dy][threadIdx.x] = f2bf(src[(size_t)(r0 + dy) * C + c0 + threadIdx.x]);
  __syncthreads();
  for (int dy = threadIdx.y; dy < 32; dy += 8)
    dst[(size_t)(c0 + dy) * R + r0 + threadIdx.x] = tile[threadIdx.x][dy];
}

// h0 (f32 [16][512] per layer) -> tagged word plane (parity 0), tag = 0
__global__ __launch_bounds__(256) void hprep_kernel(const float* __restrict__ h0,
                                                    u64* __restrict__ hbuf) {
  int l = blockIdx.x;
  const float* h = h0 + l * 8192;
  u64* buf = hbuf + (size_t)l * 2 * 2816;   // parity-0 plane
  for (int idx = threadIdx.x; idx < 2816; idx += 256) {
    int row = idx / 176, W = idx - row * 176;
    int b2 = W / 22, wi = W - b2 * 22;
    int d0 = b2 * 64 + wi * 3;
    u32 a = f2bf(h[row * 512 + d0]);
    u32 b = (wi < 21) ? f2bf(h[row * 512 + d0 + 1]) : 0;
    u32 c = (wi < 21) ? f2bf(h[row * 512 + d0 + 2]) : 0;
    buf[idx] = (u64)a | ((u64)b << 16) | ((u64)c << 32);   // tag = 0 in bits 63:48
  }
}

// LN over D=512, input [B][S][D] f32, output time-major [S][B][D] bf16
__global__ __launch_bounds__(256) void ln0_kernel(const float* __restrict__ in,
                                                  const float* __restrict__ g,
                                                  const float* __restrict__ be,
                                                  u16* __restrict__ xout) {
  int m = blockIdx.x;            // b*1024 + s
  int b = m >> 10, s = m & 1023;
  int i = threadIdx.x * 2;
  float2 v = *(const float2*)(in + (size_t)m * 512 + i);
  float sum = v.x + v.y, sq = v.x * v.x + v.y * v.y;
  for (int o = 32; o > 0; o >>= 1) { sum += __shfl_down(sum, o); sq += __shfl_down(sq, o); }
  __shared__ float red[10];
  int w = threadIdx.x >> 6, lane = threadIdx.x & 63;
  if (!lane) { red[w] = sum; red[w + 4] = sq; }
  __syncthreads();
  if (threadIdx.x == 0) {
    sum = red[0] + red[1] + red[2] + red[3];
    sq  = red[4] + red[5] + red[6] + red[7];
    float mu = sum * (1.f / 512.f), var = sq * (1.f / 512.f) - mu * mu;
    red[8] = mu; red[9] = rsqrtf(var + 1e-5f);
  }
  __syncthreads();
  float mu = red[8], rs = red[9];
  u32 o0 = (u32)f2bf((v.x - mu) * rs * g[i] + be[i]) |
           ((u32)f2bf((v.y - mu) * rs * g[i + 1] + be[i + 1]) << 16);
  *(u32*)(xout + (size_t)(s * 16 + b) * 512 + i) = o0;
}

// out = inputs + h(time-major);  y = bf16(LN(out))
__global__ __launch_bounds__(256) void resid_ln1_kernel(const float* __restrict__ in,
                                                        const u16* __restrict__ hrec,
                                                        const float* __restrict__ g,
                                                        const float* __restrict__ be,
                                                        float* __restrict__ outf,
                                                        u16* __restrict__ y) {
  int m = blockIdx.x;            // b*1024 + s
  int b = m >> 10, s = m & 1023;
  int i = threadIdx.x * 2;
  float2 v = *(const float2*)(in + (size_t)m * 512 + i);
  u32 hu = *(const u32*)(hrec + (size_t)(s * 16 + b) * 512 + i);
  v.x += bf2f((u16)(hu & 0xffff));
  v.y += bf2f((u16)(hu >> 16));
  *(float2*)(outf + (size_t)m * 512 + i) = v;
  float sum = v.x + v.y, sq = v.x * v.x + v.y * v.y;
  for (int o = 32; o > 0; o >>= 1) { sum += __shfl_down(sum, o); sq += __shfl_down(sq, o); }
  __shared__ float red[10];
  int w = threadIdx.x >> 6, lane = threadIdx.x & 63;
  if (!lane) { red[w] = sum; red[w + 4] = sq; }
  __syncthreads();
  if (threadIdx.x == 0) {
    sum = red[0] + red[1] + red[2] + red[3];
    sq  = red[4] + red[5] + red[6] + red[7];
    float mu = sum * (1.f / 512.f), var = sq * (1.f / 512.f) - mu * mu;
    red[8] = mu; red[9] = rsqrtf(var + 1e-5f);
  }
  __syncthreads();
  float mu = red[8], rs = red[9];
  u32 o0 = (u32)f2bf((v.x - mu) * rs * g[i] + be[i]) |
           ((u32)f2bf((v.y - mu) * rs * g[i + 1] + be[i + 1]) << 16);
  *(u32*)(y + (size_t)m * 512 + i) = o0;
}

// ---------------- bf16 MFMA GEMM: C[M][N] = A[M][K] * Bt[N][K]^T ----------------
// EPI 0: bf16 out = acc+bias; EPI 1: bf16 out = gelu(acc+bias); EPI 2: f32 out = acc+bias+resid
template <int EPI>
__global__ __launch_bounds__(256, 2)
void gemm_bt(const u16* __restrict__ A, const u16* __restrict__ Bt,
             void* __restrict__ Out, const float* __restrict__ bias,
             const float* __restrict__ resid, int M, int N, int K) {
  __shared__ u16 As[128 * 64];
  __shared__ u16 Bs[128 * 64];
  const int bn = blockIdx.x, bm = blockIdx.y;
  const int tid = threadIdx.x;
  const int w = tid >> 6, lane = tid & 63;
  const int wr = w >> 1, wc = w & 1;
  const int col = lane & 15, kg = lane >> 4;
  const int l8 = lane >> 3, l7 = lane & 7;
  f32x4 acc[4][4];
#pragma unroll
  for (int i = 0; i < 4; ++i)
#pragma unroll
    for (int j = 0; j < 4; ++j) acc[i][j] = (f32x4){0.f, 0.f, 0.f, 0.f};

  for (int k0 = 0; k0 < K; k0 += 64) {
    __syncthreads();
#pragma unroll
    for (int i = 0; i < 4; ++i) {
      int q = w * 4 + i;
      int row = q * 8 + l8;
      int cswz = (l7 * 16) ^ ((row & 7) << 4);
      gld16((const char*)A + ((size_t)(bm * 128 + row) * K + k0) * 2 + cswz,
            (char*)As + q * 1024);
      gld16((const char*)Bt + ((size_t)(bn * 128 + row) * K + k0) * 2 + cswz,
            (char*)Bs + q * 1024);
    }
    asm volatile("s_waitcnt vmcnt(0)" ::: "memory");
    __syncthreads();
#pragma unroll
    for (int kc = 0; kc < 2; ++kc) {
      short8 af[4], bfr[4];
      int cb = kc * 64 + kg * 16;
#pragma unroll
      for (int mi = 0; mi < 4; ++mi) {
        int r = wr * 64 + mi * 16 + col;
        af[mi] = *(const short8*)((const char*)As + r * 128 + (cb ^ ((r & 7) << 4)));
      }
#pragma unroll
      for (int ni = 0; ni < 4; ++ni) {
        int r = wc * 64 + ni * 16 + col;
        bfr[ni] = *(const short8*)((const char*)Bs + r * 128 + (cb ^ ((r & 7) << 4)));
      }
#pragma unroll
      for (int mi = 0; mi < 4; ++mi)
#pragma unroll
        for (int ni = 0; ni < 4; ++ni)
          acc[mi][ni] = __builtin_amdgcn_mfma_f32_16x16x32_bf16(af[mi], bfr[ni], acc[mi][ni], 0, 0, 0);
    }
  }
#pragma unroll
  for (int ni = 0; ni < 4; ++ni) {
    int gn = bn * 128 + wc * 64 + ni * 16 + col;
    float bv = bias ? bias[gn] : 0.f;
#pragma unroll
    for (int mi = 0; mi < 4; ++mi) {
      int gmb = bm * 128 + wr * 64 + mi * 16 + kg * 4;
#pragma unroll
      for (int j = 0; j < 4; ++j) {
        float v = acc[mi][ni][j] + bv;
        size_t idx = (size_t)(gmb + j) * N + gn;
        if (EPI == 0) {
          ((u16*)Out)[idx] = f2bf(v);
        } else if (EPI == 1) {
          float gel = 0.5f * v * (1.f + erff(v * 0.7071067811865476f));
          ((u16*)Out)[idx] = f2bf(gel);
        } else {
          ((float*)Out)[idx] = v + resid[idx];
        }
      }
    }
  }
}

// ---------------- persistent GRU recurrence (one layer) ----------------
// 8 blocks x 4 waves. Block owns d-slice [blk*64, blk*64+64).
// Cross-block h exchange: self-validating 8B words {3x bf16, u16 tag=t} via
// relaxed AGENT-scope atomics (sc1 -> device coherence point). No fences, no
// separate flag: one L3 trip per step. Parity-2 word planes; tags reset by
// memset+hprep each launch (replay-safe).
__global__ __launch_bounds__(256, 1)
void rec_kernel(const u16* __restrict__ gi, const u16* __restrict__ whh,
                const float* __restrict__ bhh, const float* __restrict__ h0,
                u64* __restrict__ lbuf, u16* __restrict__ xout) {
  __shared__ u16 hs[16 * 512];                 // gathered h(t-1), 16 KB
  __shared__ __align__(16) u16 hxB[16][64];    // block's fresh h slice bounce, 2 KB
  const int blk = blockIdx.x;
  const int tid = threadIdx.x;
  const int w = tid >> 6, lane = tid & 63;
  const int col = lane & 15, kg = lane >> 4;
  const int d = blk * 64 + w * 16 + col;

  // preload W_hh fragments: B-frag for gate g, k-chunk kc
  short8 wf0[16], wf1[16], wf2[16];
  {
    const u16* r0 = whh + (size_t)(0 * 512 + d) * 512;
    const u16* r1 = whh + (size_t)(1 * 512 + d) * 512;
    const u16* r2 = whh + (size_t)(2 * 512 + d) * 512;
#pragma unroll
    for (int kc = 0; kc < 16; ++kc) {
      wf0[kc] = *(const short8*)(r0 + kc * 32 + kg * 8);
      wf1[kc] = *(const short8*)(r1 + kc * 32 + kg * 8);
      wf2[kc] = *(const short8*)(r2 + kc * 32 + kg * 8);
    }
  }
  const float bh0 = bhh[d], bh1 = bhh[512 + d], bh2 = bhh[1024 + d];
  float hprev[4];
#pragma unroll
  for (int j = 0; j < 4; ++j) hprev[j] = h0[(kg * 4 + j) * 512 + d];

  // per-thread gather word metadata (loop-invariant): 11 words each
  const int base = tid * 11;
  int  rowA[11], dA[11];     // word row, first global d
  u32  bA[11];               // LDS byte base (pre-XOR)
  bool locA[11], w21[11];
#pragma unroll
  for (int i = 0; i < 11; ++i) {
    int idx = base + i;
    int row = idx / 176, W = idx - row * 176;
    int b2 = W / 22, wi = W - b2 * 22;
    int d0 = b2 * 64 + wi * 3;
    rowA[i] = row; dA[i] = d0;
    bA[i] = (u32)(row * 1024 + 2 * d0);
    locA[i] = (b2 == blk);
    w21[i] = (wi == 21);
  }

  for (int t = 1; t <= 1024; ++t) {
    // gi loads (independent of h) issued first to hide HBM latency under the poll
    float gir[3][4];
#pragma unroll
    for (int gte = 0; gte < 3; ++gte)
#pragma unroll
      for (int j = 0; j < 4; ++j)
        gir[gte][j] = bf2f(gi[((size_t)(t - 1) * 16 + kg * 4 + j) * 1536 + gte * 512 + d]);

    // ---- gather h(t-1) ----
    u64* rp = lbuf + (size_t)((t - 1) & 1) * 2816;
    const u16 want = (u16)(t - 1);
    const bool useloc = (t > 1);
    u64 v[11];
#pragma unroll
    for (int i = 0; i < 11; ++i)
      if (!(useloc && locA[i]))
        v[i] = __hip_atomic_load(rp + base + i, __ATOMIC_RELAXED, __HIP_MEMORY_SCOPE_AGENT);
    for (;;) {
      bool ok = true;
#pragma unroll
      for (int i = 0; i < 11; ++i)
        ok &= (useloc && locA[i]) || ((u16)(v[i] >> 48) == want);
      if (ok) break;
#pragma unroll
      for (int i = 0; i < 11; ++i)
        if (!(useloc && locA[i]) && (u16)(v[i] >> 48) != want)
          v[i] = __hip_atomic_load(rp + base + i, __ATOMIC_RELAXED, __HIP_MEMORY_SCOPE_AGENT);
    }
    if (useloc) {
#pragma unroll
      for (int i = 0; i < 11; ++i)
        if (locA[i]) {
          int dl = dA[i] - blk * 64;
          u64 a = hxB[rowA[i]][dl];
          u64 b = w21[i] ? 0 : hxB[rowA[i]][dl + 1];
          u64 c = w21[i] ? 0 : hxB[rowA[i]][dl + 2];
          v[i] = a | (b << 16) | (c << 32);
        }
    }
    // scatter payload -> hs (XOR-swizzled, matches frag-read side)
#pragma unroll
    for (int i = 0; i < 11; ++i) {
      u32 x = (u32)((rowA[i] & 7) << 4);
      hs[((bA[i]) ^ x) >> 1] = (u16)v[i];
      if (!w21[i]) {
        hs[((bA[i] + 2) ^ x) >> 1] = (u16)(v[i] >> 16);
        hs[((bA[i] + 4) ^ x) >> 1] = (u16)(v[i] >> 32);
      }
    }
    __syncthreads();

    // ---- h matvec (3 gates) ----
    f32x4 ar = {0.f, 0.f, 0.f, 0.f}, az = ar, an = ar;
#pragma unroll
    for (int kc = 0; kc < 16; ++kc) {
      int rb = col;                    // batch row
      int cb = kc * 64 + kg * 16;
      short8 a = *(const short8*)((const char*)hs + rb * 1024 + (cb ^ ((rb & 7) << 4)));
      ar = __builtin_amdgcn_mfma_f32_16x16x32_bf16(a, wf0[kc], ar, 0, 0, 0);
      az = __builtin_amdgcn_mfma_f32_16x16x32_bf16(a, wf1[kc], az, 0, 0, 0);
      an = __builtin_amdgcn_mfma_f32_16x16x32_bf16(a, wf2[kc], an, 0, 0, 0);
    }
    // gates; h stays f32 in-lane
#pragma unroll
    for (int j = 0; j < 4; ++j) {
      float rg = 1.f / (1.f + expf(-(gir[0][j] + ar[j] + bh0)));
      float zg = 1.f / (1.f + expf(-(gir[1][j] + az[j] + bh1)));
      float ng = tanhf(gir[2][j] + rg * (an[j] + bh2));
      float hn = (1.f - zg) * ng + zg * hprev[j];
      hprev[j] = hn;
      hxB[kg * 4 + j][w * 16 + col] = f2bf(hn);
    }
    __syncthreads();

    // ---- publish h(t): tagged words, one atomic store each ----
    {
      u64 tg = ((u64)(u16)t) << 48;
      u64* wp = lbuf + (size_t)(t & 1) * 2816;
      for (int widx = tid; widx < 352; widx += 256) {
        int row = widx / 22, wi = widx - row * 22;
        int dl0 = wi * 3;
        u64 a = hxB[row][dl0];
        u64 b = (wi < 21) ? hxB[row][dl0 + 1] : 0;
        u64 c = (wi < 21) ? hxB[row][dl0 + 2] : 0;
        __hip_atomic_store(wp + row * 176 + blk * 22 + wi,
                           a | (b << 16) | (c << 32) | tg,
                           __ATOMIC_RELAXED, __HIP_MEMORY_SCOPE_AGENT);
      }
      // xout (time-major bf16) for next layer / residual
      int row = tid >> 4, q = tid & 15;
      u64 pk = *(const u64*)&hxB[row][q * 4];
      *(u64*)(xout + ((size_t)(t - 1) * 16 + row) * 512 + blk * 64 + q * 4) = pk;
    }
  }
}

// ---------------- host ----------------
extern "C" void kernel_launch(void* const* d_in, const int* in_sizes, int n_in,
                              void* d_out, int out_size, void* d_ws, size_t ws_size,
                              hipStream_t stream) {
  const float* inp = (const float*)d_in[0];
  const float* h0  = (const float*)d_in[1];
  const float* wih = (const float*)d_in[2];
  const float* whh = (const float*)d_in[3];
  const float* bih = (const float*)d_in[4];
  const float* bhh = (const float*)d_in[5];
  const float* g0  = (const float*)d_in[6];
  const float* be0 = (const float*)d_in[7];
  const float* g1  = (const float*)d_in[8];
  const float* be1 = (const float*)d_in[9];
  const float* w1  = (const float*)d_in[10];
  const float* b1  = (const float*)d_in[11];
  const float* w2  = (const float*)d_in[12];
  const float* b2  = (const float*)d_in[13];
  float* out = (float*)d_out;

  char* p = (char*)d_ws;
  auto alloc = [&](size_t bytes) {
    char* r = p;
    p += (bytes + 255) & ~(size_t)255;
    return r;
  };
  u16* xa    = (u16*)alloc(16384ull * 512 * 2);
  u16* xb    = (u16*)alloc(16384ull * 512 * 2);
  u16* gib   = (u16*)alloc(16384ull * 1536 * 2);
  u16* mid   = (u16*)alloc(16384ull * 2048 * 2);
  float* outf = (float*)alloc(16384ull * 512 * 4);
  u16* wihb  = (u16*)alloc(3ull * 1536 * 512 * 2);
  u16* whhb  = (u16*)alloc(3ull * 1536 * 512 * 2);
  u16* w1t   = (u16*)alloc(2048ull * 512 * 2);
  u16* w2t   = (u16*)alloc(512ull * 2048 * 2);
  u64* hbuf  = (u64*)alloc(3ull * 2 * 2816 * 8);   // tagged word planes

  hipMemsetAsync(hbuf, 0, 3ull * 2 * 2816 * 8, stream);   // tags -> 0 (replay-safe)
  cast_kernel<<<(3 * 1536 * 512) / 1024, 256, 0, stream>>>(wih, wihb, 3 * 1536 * 512);
  cast_kernel<<<(3 * 1536 * 512) / 1024, 256, 0, stream>>>(whh, whhb, 3 * 1536 * 512);
  hprep_kernel<<<3, 256, 0, stream>>>(h0, hbuf);
  tcast_kernel<<<dim3(2048 / 32, 512 / 32), dim3(32, 8), 0, stream>>>(w1, w1t, 512, 2048);
  tcast_kernel<<<dim3(512 / 32, 2048 / 32), dim3(32, 8), 0, stream>>>(w2, w2t, 2048, 512);
  ln0_kernel<<<16384, 256, 0, stream>>>(inp, g0, be0, xa);

  for (int l = 0; l < 3; ++l) {
    const u16* xin = (l & 1) ? xb : xa;  // l0:xa l1:xb l2:xa
    u16* xo        = (l & 1) ? xa : xb;  // l0:xb l1:xa l2:xb
    gemm_bt<0><<<dim3(12, 128), 256, 0, stream>>>(xin, wihb + (size_t)l * 1536 * 512,
                                                  (void*)gib, bih + l * 1536, nullptr,
                                                  16384, 1536, 512);
    rec_kernel<<<8, 256, 0, stream>>>(gib, whhb + (size_t)l * 1536 * 512, bhh + l * 1536,
                                      h0 + l * 8192, hbuf + (size_t)l * 2 * 2816, xo);
  }
  resid_ln1_kernel<<<16384, 256, 0, stream>>>(inp, xb, g1, be1, outf, xa);
  gemm_bt<1><<<dim3(16, 128), 256, 0, stream>>>(xa, w1t, (void*)mid, b1, nullptr,
                                                16384, 2048, 512);
  gemm_bt<2><<<dim3(4, 128), 256, 0, stream>>>(mid, w2t, (void*)out, b2, outf,
                                               16384, 512, 2048);
}

// Round 3
// 14088.261 us; speedup vs baseline: 1.3739x; 1.3739x over previous
//
#include <hip/hip_runtime.h>
#include <hip/hip_bf16.h>

typedef unsigned short u16;
typedef unsigned int   u32;
typedef unsigned long long u64;
typedef __attribute__((ext_vector_type(8))) short short8;
typedef __attribute__((ext_vector_type(4))) float f32x4;

__device__ __forceinline__ float bf2f(u16 u) {
  union { u32 i; float f; } v; v.i = ((u32)u) << 16; return v.f;
}
__device__ __forceinline__ u16 f2bf(float f) {
  union { float f; u32 i; } v; v.f = f;
  return (u16)((v.i + 0x7FFFu + ((v.i >> 16) & 1u)) >> 16);
}

typedef const __attribute__((address_space(1))) u32* gas_t;
typedef __attribute__((address_space(3)))       u32* las_t;
__device__ __forceinline__ void gld16(const void* g, void* l) {
  __builtin_amdgcn_global_load_lds((gas_t)g, (las_t)l, 16, 0, 0);
}

// ---------------- elementwise prep ----------------
__global__ __launch_bounds__(256) void cast_kernel(const float* __restrict__ src,
                                                   u16* __restrict__ dst, int n) {
  int i = (blockIdx.x * 256 + threadIdx.x) * 4;
  if (i >= n) return;
  float4 v = *(const float4*)(src + i);
  uint2 o;
  o.x = (u32)f2bf(v.x) | ((u32)f2bf(v.y) << 16);
  o.y = (u32)f2bf(v.z) | ((u32)f2bf(v.w) << 16);
  *(uint2*)(dst + i) = o;
}

// dst[c][r] = bf16(src[r][c]);  R,C multiples of 32
__global__ __launch_bounds__(256) void tcast_kernel(const float* __restrict__ src,
                                                    u16* __restrict__ dst, int R, int C) {
  __shared__ u16 tile[32][33];
  int c0 = blockIdx.x * 32, r0 = blockIdx.y * 32;
  for (int dy = threadIdx.y; dy < 32; dy += 8)
    tile[dy][threadIdx.x] = f2bf(src[(size_t)(r0 + dy) * C + c0 + threadIdx.x]);
  __syncthreads();
  for (int dy = threadIdx.y; dy < 32; dy += 8)
    dst[(size_t)(c0 + dy) * R + r0 + threadIdx.x] = tile[threadIdx.x][dy];
}

// h0 (f32 [16][512] per layer) -> tagged u64 plane (parity 0), tag = 0
// plane layout: u64 word W: row = W>>8, d = (W&255)*2; word = {tag|p(d)} | {tag|p(d+1)}<<32
__global__ __launch_bounds__(256) void hprep_kernel(const float* __restrict__ h0,
                                                    u64* __restrict__ hbuf) {
  int l = blockIdx.x;
  const float* h = h0 + l * 8192;
  u64* buf = hbuf + (size_t)l * 2 * 4096;   // parity-0 plane
  for (int idx = threadIdx.x; idx < 4096; idx += 256) {
    int row = idx >> 8, wl = idx & 255;
    int d0 = wl * 2;
    u64 p0 = f2bf(h[row * 512 + d0]);
    u64 p1 = f2bf(h[row * 512 + d0 + 1]);
    buf[idx] = p0 | (p1 << 32);            // tags = 0
  }
}

// LN over D=512, input [B][S][D] f32, output time-major [S][B][D] bf16
__global__ __launch_bounds__(256) void ln0_kernel(const float* __restrict__ in,
                                                  const float* __restrict__ g,
                                                  const float* __restrict__ be,
                                                  u16* __restrict__ xout) {
  int m = blockIdx.x;            // b*1024 + s
  int b = m >> 10, s = m & 1023;
  int i = threadIdx.x * 2;
  float2 v = *(const float2*)(in + (size_t)m * 512 + i);
  float sum = v.x + v.y, sq = v.x * v.x + v.y * v.y;
  for (int o = 32; o > 0; o >>= 1) { sum += __shfl_down(sum, o); sq += __shfl_down(sq, o); }
  __shared__ float red[10];
  int w = threadIdx.x >> 6, lane = threadIdx.x & 63;
  if (!lane) { red[w] = sum; red[w + 4] = sq; }
  __syncthreads();
  if (threadIdx.x == 0) {
    sum = red[0] + red[1] + red[2] + red[3];
    sq  = red[4] + red[5] + red[6] + red[7];
    float mu = sum * (1.f / 512.f), var = sq * (1.f / 512.f) - mu * mu;
    red[8] = mu; red[9] = rsqrtf(var + 1e-5f);
  }
  __syncthreads();
  float mu = red[8], rs = red[9];
  u32 o0 = (u32)f2bf((v.x - mu) * rs * g[i] + be[i]) |
           ((u32)f2bf((v.y - mu) * rs * g[i + 1] + be[i + 1]) << 16);
  *(u32*)(xout + (size_t)(s * 16 + b) * 512 + i) = o0;
}

// out = inputs + h(time-major);  y = bf16(LN(out))
__global__ __launch_bounds__(256) void resid_ln1_kernel(const float* __restrict__ in,
                                                        const u16* __restrict__ hrec,
                                                        const float* __restrict__ g,
                                                        const float* __restrict__ be,
                                                        float* __restrict__ outf,
                                                        u16* __restrict__ y) {
  int m = blockIdx.x;            // b*1024 + s
  int b = m >> 10, s = m & 1023;
  int i = threadIdx.x * 2;
  float2 v = *(const float2*)(in + (size_t)m * 512 + i);
  u32 hu = *(const u32*)(hrec + (size_t)(s * 16 + b) * 512 + i);
  v.x += bf2f((u16)(hu & 0xffff));
  v.y += bf2f((u16)(hu >> 16));
  *(float2*)(outf + (size_t)m * 512 + i) = v;
  float sum = v.x + v.y, sq = v.x * v.x + v.y * v.y;
  for (int o = 32; o > 0; o >>= 1) { sum += __shfl_down(sum, o); sq += __shfl_down(sq, o); }
  __shared__ float red[10];
  int w = threadIdx.x >> 6, lane = threadIdx.x & 63;
  if (!lane) { red[w] = sum; red[w + 4] = sq; }
  __syncthreads();
  if (threadIdx.x == 0) {
    sum = red[0] + red[1] + red[2] + red[3];
    sq  = red[4] + red[5] + red[6] + red[7];
    float mu = sum * (1.f / 512.f), var = sq * (1.f / 512.f) - mu * mu;
    red[8] = mu; red[9] = rsqrtf(var + 1e-5f);
  }
  __syncthreads();
  float mu = red[8], rs = red[9];
  u32 o0 = (u32)f2bf((v.x - mu) * rs * g[i] + be[i]) |
           ((u32)f2bf((v.y - mu) * rs * g[i + 1] + be[i + 1]) << 16);
  *(u32*)(y + (size_t)m * 512 + i) = o0;
}

// ---------------- bf16 MFMA GEMM: C[M][N] = A[M][K] * Bt[N][K]^T ----------------
// EPI 0: bf16 out = acc+bias; EPI 1: bf16 out = gelu(acc+bias); EPI 2: f32 out = acc+bias+resid
template <int EPI>
__global__ __launch_bounds__(256, 2)
void gemm_bt(const u16* __restrict__ A, const u16* __restrict__ Bt,
             void* __restrict__ Out, const float* __restrict__ bias,
             const float* __restrict__ resid, int M, int N, int K) {
  __shared__ u16 As[128 * 64];
  __shared__ u16 Bs[128 * 64];
  const int bn = blockIdx.x, bm = blockIdx.y;
  const int tid = threadIdx.x;
  const int w = tid >> 6, lane = tid & 63;
  const int wr = w >> 1, wc = w & 1;
  const int col = lane & 15, kg = lane >> 4;
  const int l8 = lane >> 3, l7 = lane & 7;
  f32x4 acc[4][4];
#pragma unroll
  for (int i = 0; i < 4; ++i)
#pragma unroll
    for (int j = 0; j < 4; ++j) acc[i][j] = (f32x4){0.f, 0.f, 0.f, 0.f};

  for (int k0 = 0; k0 < K; k0 += 64) {
    __syncthreads();
#pragma unroll
    for (int i = 0; i < 4; ++i) {
      int q = w * 4 + i;
      int row = q * 8 + l8;
      int cswz = (l7 * 16) ^ ((row & 7) << 4);
      gld16((const char*)A + ((size_t)(bm * 128 + row) * K + k0) * 2 + cswz,
            (char*)As + q * 1024);
      gld16((const char*)Bt + ((size_t)(bn * 128 + row) * K + k0) * 2 + cswz,
            (char*)Bs + q * 1024);
    }
    asm volatile("s_waitcnt vmcnt(0)" ::: "memory");
    __syncthreads();
#pragma unroll
    for (int kc = 0; kc < 2; ++kc) {
      short8 af[4], bfr[4];
      int cb = kc * 64 + kg * 16;
#pragma unroll
      for (int mi = 0; mi < 4; ++mi) {
        int r = wr * 64 + mi * 16 + col;
        af[mi] = *(const short8*)((const char*)As + r * 128 + (cb ^ ((r & 7) << 4)));
      }
#pragma unroll
      for (int ni = 0; ni < 4; ++ni) {
        int r = wc * 64 + ni * 16 + col;
        bfr[ni] = *(const short8*)((const char*)Bs + r * 128 + (cb ^ ((r & 7) << 4)));
      }
#pragma unroll
      for (int mi = 0; mi < 4; ++mi)
#pragma unroll
        for (int ni = 0; ni < 4; ++ni)
          acc[mi][ni] = __builtin_amdgcn_mfma_f32_16x16x32_bf16(af[mi], bfr[ni], acc[mi][ni], 0, 0, 0);
    }
  }
#pragma unroll
  for (int ni = 0; ni < 4; ++ni) {
    int gn = bn * 128 + wc * 64 + ni * 16 + col;
    float bv = bias ? bias[gn] : 0.f;
#pragma unroll
    for (int mi = 0; mi < 4; ++mi) {
      int gmb = bm * 128 + wr * 64 + mi * 16 + kg * 4;
#pragma unroll
      for (int j = 0; j < 4; ++j) {
        float v = acc[mi][ni][j] + bv;
        size_t idx = (size_t)(gmb + j) * N + gn;
        if (EPI == 0) {
          ((u16*)Out)[idx] = f2bf(v);
        } else if (EPI == 1) {
          float gel = 0.5f * v * (1.f + erff(v * 0.7071067811865476f));
          ((u16*)Out)[idx] = f2bf(gel);
        } else {
          ((float*)Out)[idx] = v + resid[idx];
        }
      }
    }
  }
}

// ---------------- persistent GRU recurrence (one layer) ----------------
// 8 blocks x 4 waves. Block owns d-slice [blk*64, blk*64+64).
// Exchange: self-validating tagged u64 words {p(2W)|tag, p(2W+1)|tag} via relaxed
// AGENT-scope atomics. Single CP round trip, no fences, no flags. Producer
// publishes STRAIGHT FROM REGISTERS (shfl_xor packing, no LDS bounce, no
// pre-publish barrier). Consumer gathers coalesced u64x16/thread, repacks to
// uint4, stages via ds_write_b128 at the MFMA read swizzle.
__global__ __launch_bounds__(256, 1)
void rec_kernel(const u16* __restrict__ gi, const u16* __restrict__ whh,
                const float* __restrict__ bhh, const float* __restrict__ h0,
                u64* __restrict__ lbuf, u16* __restrict__ xout) {
  __shared__ u16 hs[16 * 512];                 // gathered h(t-1), swizzled, 16 KB
  const int blk = blockIdx.x;
  const int tid = threadIdx.x;
  const int w = tid >> 6, lane = tid & 63;
  const int col = lane & 15, kg = lane >> 4;
  const int d = blk * 64 + w * 16 + col;

  // preload W_hh fragments: B-frag for gate g, k-chunk kc
  short8 wf0[16], wf1[16], wf2[16];
  {
    const u16* r0 = whh + (size_t)(0 * 512 + d) * 512;
    const u16* r1 = whh + (size_t)(1 * 512 + d) * 512;
    const u16* r2 = whh + (size_t)(2 * 512 + d) * 512;
#pragma unroll
    for (int kc = 0; kc < 16; ++kc) {
      wf0[kc] = *(const short8*)(r0 + kc * 32 + kg * 8);
      wf1[kc] = *(const short8*)(r1 + kc * 32 + kg * 8);
      wf2[kc] = *(const short8*)(r2 + kc * 32 + kg * 8);
    }
  }
  const float bh0 = bhh[d], bh1 = bhh[512 + d], bh2 = bhh[1024 + d];
  float hprev[4];
#pragma unroll
  for (int j = 0; j < 4; ++j) hprev[j] = h0[(kg * 4 + j) * 512 + d];

  const bool ev = !(col & 1);
  const u64 TM = 0xFFFF0000FFFF0000ULL;

  for (int t = 1; t <= 1024; ++t) {
    // gi loads (independent of h) issued first to hide HBM latency under the poll
    float gir[3][4];
#pragma unroll
    for (int gte = 0; gte < 3; ++gte)
#pragma unroll
      for (int j = 0; j < 4; ++j)
        gir[gte][j] = bf2f(gi[((size_t)(t - 1) * 16 + kg * 4 + j) * 1536 + gte * 512 + d]);

    // ---- gather h(t-1): 16 tagged u64, coalesced (4 rows x 32B/lane) ----
    u64* rp = lbuf + (size_t)((t - 1) & 1) * 4096;
    const u32 want = (u32)(t - 1);
    const u64 exp = ((u64)want << 16) | ((u64)want << 48);
    u64 v[16];
#pragma unroll
    for (int r = 0; r < 4; ++r)
#pragma unroll
      for (int q = 0; q < 4; ++q)
        v[r * 4 + q] = __hip_atomic_load(rp + (size_t)(w * 4 + r) * 256 + lane * 4 + q,
                                         __ATOMIC_RELAXED, __HIP_MEMORY_SCOPE_AGENT);
    for (;;) {
      bool ok = true;
#pragma unroll
      for (int i = 0; i < 16; ++i) ok &= ((v[i] ^ exp) & TM) == 0;
      if (ok) break;
      __builtin_amdgcn_s_sleep(1);
#pragma unroll
      for (int i = 0; i < 16; ++i)
        if (((v[i] ^ exp) & TM) != 0)
          v[i] = __hip_atomic_load(rp + (size_t)(w * 4 + (i >> 2)) * 256 + lane * 4 + (i & 3),
                                   __ATOMIC_RELAXED, __HIP_MEMORY_SCOPE_AGENT);
    }
    // repack payloads -> uint4, one swizzled ds_write_b128 per row
#pragma unroll
    for (int r = 0; r < 4; ++r) {
      int row = w * 4 + r;
      uint4 pk;
      pk.x = ((u32)v[r * 4 + 0] & 0xFFFFu) | ((u32)(v[r * 4 + 0] >> 32) << 16);
      pk.y = ((u32)v[r * 4 + 1] & 0xFFFFu) | ((u32)(v[r * 4 + 1] >> 32) << 16);
      pk.z = ((u32)v[r * 4 + 2] & 0xFFFFu) | ((u32)(v[r * 4 + 2] >> 32) << 16);
      pk.w = ((u32)v[r * 4 + 3] & 0xFFFFu) | ((u32)(v[r * 4 + 3] >> 32) << 16);
      *(uint4*)((char*)hs + row * 1024 + ((lane * 16) ^ ((row & 7) << 4))) = pk;
    }
    __syncthreads();

    // ---- h matvec (3 gates) ----
    f32x4 ar = {0.f, 0.f, 0.f, 0.f}, az = ar, an = ar;
#pragma unroll
    for (int kc = 0; kc < 16; ++kc) {
      int rb = col;                    // batch row
      int cb = kc * 64 + kg * 16;
      short8 a = *(const short8*)((const char*)hs + rb * 1024 + (cb ^ ((rb & 7) << 4)));
      ar = __builtin_amdgcn_mfma_f32_16x16x32_bf16(a, wf0[kc], ar, 0, 0, 0);
      az = __builtin_amdgcn_mfma_f32_16x16x32_bf16(a, wf1[kc], az, 0, 0, 0);
      an = __builtin_amdgcn_mfma_f32_16x16x32_bf16(a, wf2[kc], an, 0, 0, 0);
    }
    // gates; h stays f32 in-lane
    u32 po[4];
#pragma unroll
    for (int j = 0; j < 4; ++j) {
      float rg = 1.f / (1.f + expf(-(gir[0][j] + ar[j] + bh0)));
      float zg = 1.f / (1.f + expf(-(gir[1][j] + az[j] + bh1)));
      float ng = tanhf(gir[2][j] + rg * (an[j] + bh2));
      float hn = (1.f - zg) * ng + zg * hprev[j];
      hprev[j] = hn;
      po[j] = (u32)f2bf(hn);
    }

    // ---- publish h(t) straight from registers (no barrier needed) ----
    {
      const u32 tg = (u32)t << 16;
      u64* wp = lbuf + (size_t)(t & 1) * 4096;
      u32 pn[4], pr[4], qr[4];
#pragma unroll
      for (int j = 0; j < 4; ++j) pn[j] = (u32)__shfl_xor((int)po[j], 1);
      // tagged words (this lane's col pair), even lane stores j=0,1; odd j=2,3
      int j0 = ev ? 0 : 2;
#pragma unroll
      for (int jj = 0; jj < 2; ++jj) {
        int j = j0 + jj;
        u32 lo = (ev ? po[j] : pn[j]) | tg;
        u32 hi = (ev ? pn[j] : po[j]) | tg;
        int row = kg * 4 + j;
        __hip_atomic_store(wp + (size_t)row * 256 + blk * 32 + w * 8 + (col >> 1),
                           (u64)lo | ((u64)hi << 32),
                           __ATOMIC_RELAXED, __HIP_MEMORY_SCOPE_AGENT);
      }
      // xout: quad-pack 4 cols per u64, lane (col&3) stores row kg*4+(col&3)
#pragma unroll
      for (int j = 0; j < 4; ++j) {
        pr[j] = ev ? (po[j] | (pn[j] << 16)) : (pn[j] | (po[j] << 16));
        qr[j] = (u32)__shfl_xor((int)pr[j], 2);
      }
      int jx = col & 3;
      u64 raw = ((col & 2) == 0) ? ((u64)pr[jx] | ((u64)qr[jx] << 32))
                                 : ((u64)qr[jx] | ((u64)pr[jx] << 32));
      int row = kg * 4 + jx;
      *(u64*)(xout + ((size_t)(t - 1) * 16 + row) * 512 + blk * 64 + w * 16 + (col & ~3)) = raw;
    }
    __syncthreads();   // protect hs until all waves' MFMA reads of this step done
  }
}

// ---------------- host ----------------
extern "C" void kernel_launch(void* const* d_in, const int* in_sizes, int n_in,
                              void* d_out, int out_size, void* d_ws, size_t ws_size,
                              hipStream_t stream) {
  const float* inp = (const float*)d_in[0];
  const float* h0  = (const float*)d_in[1];
  const float* wih = (const float*)d_in[2];
  const float* whh = (const float*)d_in[3];
  const float* bih = (const float*)d_in[4];
  const float* bhh = (const float*)d_in[5];
  const float* g0  = (const float*)d_in[6];
  const float* be0 = (const float*)d_in[7];
  const float* g1  = (const float*)d_in[8];
  const float* be1 = (const float*)d_in[9];
  const float* w1  = (const float*)d_in[10];
  const float* b1  = (const float*)d_in[11];
  const float* w2  = (const float*)d_in[12];
  const float* b2  = (const float*)d_in[13];
  float* out = (float*)d_out;

  char* p = (char*)d_ws;
  auto alloc = [&](size_t bytes) {
    char* r = p;
    p += (bytes + 255) & ~(size_t)255;
    return r;
  };
  u16* xa    = (u16*)alloc(16384ull * 512 * 2);
  u16* xb    = (u16*)alloc(16384ull * 512 * 2);
  u16* gib   = (u16*)alloc(16384ull * 1536 * 2);
  u16* mid   = (u16*)alloc(16384ull * 2048 * 2);
  float* outf = (float*)alloc(16384ull * 512 * 4);
  u16* wihb  = (u16*)alloc(3ull * 1536 * 512 * 2);
  u16* whhb  = (u16*)alloc(3ull * 1536 * 512 * 2);
  u16* w1t   = (u16*)alloc(2048ull * 512 * 2);
  u16* w2t   = (u16*)alloc(512ull * 2048 * 2);
  u64* hbuf  = (u64*)alloc(3ull * 2 * 4096 * 8);   // tagged u64 planes

  hipMemsetAsync(hbuf, 0, 3ull * 2 * 4096 * 8, stream);   // tags -> 0 (replay-safe)
  cast_kernel<<<(3 * 1536 * 512) / 1024, 256, 0, stream>>>(wih, wihb, 3 * 1536 * 512);
  cast_kernel<<<(3 * 1536 * 512) / 1024, 256, 0, stream>>>(whh, whhb, 3 * 1536 * 512);
  hprep_kernel<<<3, 256, 0, stream>>>(h0, hbuf);
  tcast_kernel<<<dim3(2048 / 32, 512 / 32), dim3(32, 8), 0, stream>>>(w1, w1t, 512, 2048);
  tcast_kernel<<<dim3(512 / 32, 2048 / 32), dim3(32, 8), 0, stream>>>(w2, w2t, 2048, 512);
  ln0_kernel<<<16384, 256, 0, stream>>>(inp, g0, be0, xa);

  for (int l = 0; l < 3; ++l) {
    const u16* xin = (l & 1) ? xb : xa;  // l0:xa l1:xb l2:xa
    u16* xo        = (l & 1) ? xa : xb;  // l0:xb l1:xa l2:xb
    gemm_bt<0><<<dim3(12, 128), 256, 0, stream>>>(xin, wihb + (size_t)l * 1536 * 512,
                                                  (void*)gib, bih + l * 1536, nullptr,
                                                  16384, 1536, 512);
    rec_kernel<<<8, 256, 0, stream>>>(gib, whhb + (size_t)l * 1536 * 512, bhh + l * 1536,
                                      h0 + l * 8192, hbuf + (size_t)l * 2 * 4096, xo);
  }
  resid_ln1_kernel<<<16384, 256, 0, stream>>>(inp, xb, g1, be1, outf, xa);
  gemm_bt<1><<<dim3(16, 128), 256, 0, stream>>>(xa, w1t, (void*)mid, b1, nullptr,
                                                16384, 2048, 512);
  gemm_bt<2><<<dim3(4, 128), 256, 0, stream>>>(mid, w2t, (void*)out, b2, outf,
                                               16384, 512, 2048);
}

// Round 4
// 7712.425 us; speedup vs baseline: 2.5098x; 1.8267x over previous
//
#include <hip/hip_runtime.h>
#include <hip/hip_bf16.h>

typedef unsigned short u16;
typedef unsigned int   u32;
typedef unsigned long long u64;
typedef __attribute__((ext_vector_type(8))) short short8;
typedef __attribute__((ext_vector_type(4))) float f32x4;

__device__ __forceinline__ float bf2f(u16 u) {
  union { u32 i; float f; } v; v.i = ((u32)u) << 16; return v.f;
}
__device__ __forceinline__ u16 f2bf(float f) {
  union { float f; u32 i; } v; v.f = f;
  return (u16)((v.i + 0x7FFFu + ((v.i >> 16) & 1u)) >> 16);
}

typedef const __attribute__((address_space(1))) u32* gas_t;
typedef __attribute__((address_space(3)))       u32* las_t;
__device__ __forceinline__ void gld16(const void* g, void* l) {
  __builtin_amdgcn_global_load_lds((gas_t)g, (las_t)l, 16, 0, 0);
}

// ---------------- elementwise prep ----------------
__global__ __launch_bounds__(256) void cast_kernel(const float* __restrict__ src,
                                                   u16* __restrict__ dst, int n) {
  int i = (blockIdx.x * 256 + threadIdx.x) * 4;
  if (i >= n) return;
  float4 v = *(const float4*)(src + i);
  uint2 o;
  o.x = (u32)f2bf(v.x) | ((u32)f2bf(v.y) << 16);
  o.y = (u32)f2bf(v.z) | ((u32)f2bf(v.w) << 16);
  *(uint2*)(dst + i) = o;
}

// dst[c][r] = bf16(src[r][c]);  R,C multiples of 32
__global__ __launch_bounds__(256) void tcast_kernel(const float* __restrict__ src,
                                                    u16* __restrict__ dst, int R, int C) {
  __shared__ u16 tile[32][33];
  int c0 = blockIdx.x * 32, r0 = blockIdx.y * 32;
  for (int dy = threadIdx.y; dy < 32; dy += 8)
    tile[dy][threadIdx.x] = f2bf(src[(size_t)(r0 + dy) * C + c0 + threadIdx.x]);
  __syncthreads();
  for (int dy = threadIdx.y; dy < 32; dy += 8)
    dst[(size_t)(c0 + dy) * R + r0 + threadIdx.x] = tile[threadIdx.x][dy];
}

// h0 (f32 [16][512] per layer) -> tagged u64 plane (parity 0), tag = 0
// word W: row = W>>8, d = (W&255)*2; word = {tag16|p(d)} | {tag16|p(d+1)}<<32
__global__ __launch_bounds__(256) void hprep_kernel(const float* __restrict__ h0,
                                                    u64* __restrict__ hbuf) {
  int l = blockIdx.x;
  const float* h = h0 + l * 8192;
  u64* buf = hbuf + (size_t)l * 2 * 4096;   // parity-0 plane
  for (int idx = threadIdx.x; idx < 4096; idx += 256) {
    int row = idx >> 8, wl = idx & 255;
    int d0 = wl * 2;
    u64 p0 = f2bf(h[row * 512 + d0]);
    u64 p1 = f2bf(h[row * 512 + d0 + 1]);
    buf[idx] = p0 | (p1 << 32);            // tags = 0
  }
}

// LN over D=512, input [B][S][D] f32, output time-major [S][B][D] bf16
__global__ __launch_bounds__(256) void ln0_kernel(const float* __restrict__ in,
                                                  const float* __restrict__ g,
                                                  const float* __restrict__ be,
                                                  u16* __restrict__ xout) {
  int m = blockIdx.x;            // b*1024 + s
  int b = m >> 10, s = m & 1023;
  int i = threadIdx.x * 2;
  float2 v = *(const float2*)(in + (size_t)m * 512 + i);
  float sum = v.x + v.y, sq = v.x * v.x + v.y * v.y;
  for (int o = 32; o > 0; o >>= 1) { sum += __shfl_down(sum, o); sq += __shfl_down(sq, o); }
  __shared__ float red[10];
  int w = threadIdx.x >> 6, lane = threadIdx.x & 63;
  if (!lane) { red[w] = sum; red[w + 4] = sq; }
  __syncthreads();
  if (threadIdx.x == 0) {
    sum = red[0] + red[1] + red[2] + red[3];
    sq  = red[4] + red[5] + red[6] + red[7];
    float mu = sum * (1.f / 512.f), var = sq * (1.f / 512.f) - mu * mu;
    red[8] = mu; red[9] = rsqrtf(var + 1e-5f);
  }
  __syncthreads();
  float mu = red[8], rs = red[9];
  u32 o0 = (u32)f2bf((v.x - mu) * rs * g[i] + be[i]) |
           ((u32)f2bf((v.y - mu) * rs * g[i + 1] + be[i + 1]) << 16);
  *(u32*)(xout + (size_t)(s * 16 + b) * 512 + i) = o0;
}

// out = inputs + h(time-major);  y = bf16(LN(out))
__global__ __launch_bounds__(256) void resid_ln1_kernel(const float* __restrict__ in,
                                                        const u16* __restrict__ hrec,
                                                        const float* __restrict__ g,
                                                        const float* __restrict__ be,
                                                        float* __restrict__ outf,
                                                        u16* __restrict__ y) {
  int m = blockIdx.x;            // b*1024 + s
  int b = m >> 10, s = m & 1023;
  int i = threadIdx.x * 2;
  float2 v = *(const float2*)(in + (size_t)m * 512 + i);
  u32 hu = *(const u32*)(hrec + (size_t)(s * 16 + b) * 512 + i);
  v.x += bf2f((u16)(hu & 0xffff));
  v.y += bf2f((u16)(hu >> 16));
  *(float2*)(outf + (size_t)m * 512 + i) = v;
  float sum = v.x + v.y, sq = v.x * v.x + v.y * v.y;
  for (int o = 32; o > 0; o >>= 1) { sum += __shfl_down(sum, o); sq += __shfl_down(sq, o); }
  __shared__ float red[10];
  int w = threadIdx.x >> 6, lane = threadIdx.x & 63;
  if (!lane) { red[w] = sum; red[w + 4] = sq; }
  __syncthreads();
  if (threadIdx.x == 0) {
    sum = red[0] + red[1] + red[2] + red[3];
    sq  = red[4] + red[5] + red[6] + red[7];
    float mu = sum * (1.f / 512.f), var = sq * (1.f / 512.f) - mu * mu;
    red[8] = mu; red[9] = rsqrtf(var + 1e-5f);
  }
  __syncthreads();
  float mu = red[8], rs = red[9];
  u32 o0 = (u32)f2bf((v.x - mu) * rs * g[i] + be[i]) |
           ((u32)f2bf((v.y - mu) * rs * g[i + 1] + be[i + 1]) << 16);
  *(u32*)(y + (size_t)m * 512 + i) = o0;
}

// ---------------- bf16 MFMA GEMM: C[M][N] = A[M][K] * Bt[N][K]^T ----------------
template <int EPI>
__global__ __launch_bounds__(256, 2)
void gemm_bt(const u16* __restrict__ A, const u16* __restrict__ Bt,
             void* __restrict__ Out, const float* __restrict__ bias,
             const float* __restrict__ resid, int M, int N, int K) {
  __shared__ u16 As[128 * 64];
  __shared__ u16 Bs[128 * 64];
  const int bn = blockIdx.x, bm = blockIdx.y;
  const int tid = threadIdx.x;
  const int w = tid >> 6, lane = tid & 63;
  const int wr = w >> 1, wc = w & 1;
  const int col = lane & 15, kg = lane >> 4;
  const int l8 = lane >> 3, l7 = lane & 7;
  f32x4 acc[4][4];
#pragma unroll
  for (int i = 0; i < 4; ++i)
#pragma unroll
    for (int j = 0; j < 4; ++j) acc[i][j] = (f32x4){0.f, 0.f, 0.f, 0.f};

  for (int k0 = 0; k0 < K; k0 += 64) {
    __syncthreads();
#pragma unroll
    for (int i = 0; i < 4; ++i) {
      int q = w * 4 + i;
      int row = q * 8 + l8;
      int cswz = (l7 * 16) ^ ((row & 7) << 4);
      gld16((const char*)A + ((size_t)(bm * 128 + row) * K + k0) * 2 + cswz,
            (char*)As + q * 1024);
      gld16((const char*)Bt + ((size_t)(bn * 128 + row) * K + k0) * 2 + cswz,
            (char*)Bs + q * 1024);
    }
    asm volatile("s_waitcnt vmcnt(0)" ::: "memory");
    __syncthreads();
#pragma unroll
    for (int kc = 0; kc < 2; ++kc) {
      short8 af[4], bfr[4];
      int cb = kc * 64 + kg * 16;
#pragma unroll
      for (int mi = 0; mi < 4; ++mi) {
        int r = wr * 64 + mi * 16 + col;
        af[mi] = *(const short8*)((const char*)As + r * 128 + (cb ^ ((r & 7) << 4)));
      }
#pragma unroll
      for (int ni = 0; ni < 4; ++ni) {
        int r = wc * 64 + ni * 16 + col;
        bfr[ni] = *(const short8*)((const char*)Bs + r * 128 + (cb ^ ((r & 7) << 4)));
      }
#pragma unroll
      for (int mi = 0; mi < 4; ++mi)
#pragma unroll
        for (int ni = 0; ni < 4; ++ni)
          acc[mi][ni] = __builtin_amdgcn_mfma_f32_16x16x32_bf16(af[mi], bfr[ni], acc[mi][ni], 0, 0, 0);
    }
  }
#pragma unroll
  for (int ni = 0; ni < 4; ++ni) {
    int gn = bn * 128 + wc * 64 + ni * 16 + col;
    float bv = bias ? bias[gn] : 0.f;
#pragma unroll
    for (int mi = 0; mi < 4; ++mi) {
      int gmb = bm * 128 + wr * 64 + mi * 16 + kg * 4;
#pragma unroll
      for (int j = 0; j < 4; ++j) {
        float v = acc[mi][ni][j] + bv;
        size_t idx = (size_t)(gmb + j) * N + gn;
        if (EPI == 0) {
          ((u16*)Out)[idx] = f2bf(v);
        } else if (EPI == 1) {
          float gel = 0.5f * v * (1.f + erff(v * 0.7071067811865476f));
          ((u16*)Out)[idx] = f2bf(gel);
        } else {
          ((float*)Out)[idx] = v + resid[idx];
        }
      }
    }
  }
}

// ---------------- gather/poll helper: tagged u64 plane -> swizzled LDS ----------------
__device__ __forceinline__ void gather_poll(const u64* __restrict__ plane, u32 want,
                                            int w, int lane, u16* __restrict__ lds) {
  const u64 TM = 0xFFFF0000FFFF0000ULL;
  const u64 ex = ((u64)want << 16) | ((u64)want << 48);
  u64 v[16];
#pragma unroll
  for (int r = 0; r < 4; ++r)
#pragma unroll
    for (int q = 0; q < 4; ++q)
      v[r * 4 + q] = __hip_atomic_load(plane + (size_t)(w * 4 + r) * 256 + lane * 4 + q,
                                       __ATOMIC_RELAXED, __HIP_MEMORY_SCOPE_AGENT);
  for (;;) {
    bool ok = true;
#pragma unroll
    for (int i = 0; i < 16; ++i) ok &= ((v[i] ^ ex) & TM) == 0;
    if (ok) break;
    __builtin_amdgcn_s_sleep(1);
#pragma unroll
    for (int i = 0; i < 16; ++i)
      if (((v[i] ^ ex) & TM) != 0)
        v[i] = __hip_atomic_load(plane + (size_t)(w * 4 + (i >> 2)) * 256 + lane * 4 + (i & 3),
                                 __ATOMIC_RELAXED, __HIP_MEMORY_SCOPE_AGENT);
  }
#pragma unroll
  for (int r = 0; r < 4; ++r) {
    int row = w * 4 + r;
    uint4 pk;
    pk.x = ((u32)v[r * 4 + 0] & 0xFFFFu) | ((u32)(v[r * 4 + 0] >> 32) << 16);
    pk.y = ((u32)v[r * 4 + 1] & 0xFFFFu) | ((u32)(v[r * 4 + 1] >> 32) << 16);
    pk.z = ((u32)v[r * 4 + 2] & 0xFFFFu) | ((u32)(v[r * 4 + 2] >> 32) << 16);
    pk.w = ((u32)v[r * 4 + 3] & 0xFFFFu) | ((u32)(v[r * 4 + 3] >> 32) << 16);
    *(uint4*)((char*)lds + row * 1024 + ((lane * 16) ^ ((row & 7) << 4))) = pk;
  }
}

// ---------------- fused 3-layer persistent GRU, wavefront-pipelined ----------------
// 24 blocks: layer = blockIdx>>3, blk = blockIdx&7. Per layer: 8-block tagged-word
// h exchange (as before). Cross-layer: depth-8 x-ring; layer l>0 computes gi on the
// fly (W_ih register-resident); x-gather + gi-MFMA for step t+1 run at the tail of
// step t (hidden in the own-h wait). Back-pressure: consumer's own-h tags (>= t-8),
// prefetched off the critical path. Only layer 2 writes xout to HBM.
__global__ __launch_bounds__(256, 1)
void rec3_kernel(const u16* __restrict__ gib, const u16* __restrict__ whhb,
                 const u16* __restrict__ wihb, const float* __restrict__ bih,
                 const float* __restrict__ bhh, const float* __restrict__ h0,
                 u64* __restrict__ hpl, u64* __restrict__ xr,
                 u16* __restrict__ xout) {
  __shared__ u16 hs[16 * 512];    // h(t-1) staged
  __shared__ u16 hs2[16 * 512];   // x(t+1) staged (layers 1,2)
  const int l = blockIdx.x >> 3, blk = blockIdx.x & 7;
  const int tid = threadIdx.x;
  const int w = tid >> 6, lane = tid & 63;
  const int col = lane & 15, kg = lane >> 4;
  const int d = blk * 64 + w * 16 + col;

  const u16* whh = whhb + (size_t)l * 1536 * 512;
  const u16* wih = wihb + (size_t)l * 1536 * 512;

  // W_hh fragments (always), W_ih fragments (layers 1,2)
  short8 wh0[16], wh1[16], wh2[16];
  {
    const u16* r0 = whh + (size_t)(0 * 512 + d) * 512;
    const u16* r1 = whh + (size_t)(1 * 512 + d) * 512;
    const u16* r2 = whh + (size_t)(2 * 512 + d) * 512;
#pragma unroll
    for (int kc = 0; kc < 16; ++kc) {
      wh0[kc] = *(const short8*)(r0 + kc * 32 + kg * 8);
      wh1[kc] = *(const short8*)(r1 + kc * 32 + kg * 8);
      wh2[kc] = *(const short8*)(r2 + kc * 32 + kg * 8);
    }
  }
  short8 wi0[16], wi1[16], wi2[16];
  if (l > 0) {
    const u16* r0 = wih + (size_t)(0 * 512 + d) * 512;
    const u16* r1 = wih + (size_t)(1 * 512 + d) * 512;
    const u16* r2 = wih + (size_t)(2 * 512 + d) * 512;
#pragma unroll
    for (int kc = 0; kc < 16; ++kc) {
      wi0[kc] = *(const short8*)(r0 + kc * 32 + kg * 8);
      wi1[kc] = *(const short8*)(r1 + kc * 32 + kg * 8);
      wi2[kc] = *(const short8*)(r2 + kc * 32 + kg * 8);
    }
  }
  const float bh0 = bhh[l * 1536 + d], bh1 = bhh[l * 1536 + 512 + d],
              bh2 = bhh[l * 1536 + 1024 + d];
  float bi0 = 0.f, bi1 = 0.f, bi2 = 0.f;
  if (l > 0) {
    bi0 = bih[l * 1536 + d]; bi1 = bih[l * 1536 + 512 + d]; bi2 = bih[l * 1536 + 1024 + d];
  }
  float hprev[4];
#pragma unroll
  for (int j = 0; j < 4; ++j) hprev[j] = h0[l * 8192 + (kg * 4 + j) * 512 + d];

  u64* ownp = hpl + (size_t)l * 2 * 4096;
  const u64* upx = xr + (size_t)(l - 1) * 8 * 4096;   // valid for l>0
  u64* dnx = xr + (size_t)l * 8 * 4096;               // valid for l<2
  const u64* consp = hpl + (size_t)(l + 1) * 2 * 4096; // valid for l<2

  const bool ev = !(col & 1);
  f32x4 gr_ = {0.f, 0.f, 0.f, 0.f}, gz_ = gr_, gn_ = gr_;  // next-step gi (l>0)
  u64 bpv = 0;

  // prologue (l>0): gather x(1), compute gi(1)
  if (l > 0) {
    gather_poll(upx + 1 * 4096, 1u, w, lane, hs2);
    __syncthreads();
#pragma unroll
    for (int kc = 0; kc < 16; ++kc) {
      int cb = kc * 64 + kg * 16;
      short8 a = *(const short8*)((const char*)hs2 + col * 1024 + (cb ^ ((col & 7) << 4)));
      gr_ = __builtin_amdgcn_mfma_f32_16x16x32_bf16(a, wi0[kc], gr_, 0, 0, 0);
      gz_ = __builtin_amdgcn_mfma_f32_16x16x32_bf16(a, wi1[kc], gz_, 0, 0, 0);
      gn_ = __builtin_amdgcn_mfma_f32_16x16x32_bf16(a, wi2[kc], gn_, 0, 0, 0);
    }
  }

  for (int t = 1; t <= 1024; ++t) {
    float gir[3][4];
    if (l == 0) {
#pragma unroll
      for (int gte = 0; gte < 3; ++gte)
#pragma unroll
        for (int j = 0; j < 4; ++j)
          gir[gte][j] = bf2f(gib[((size_t)(t - 1) * 16 + kg * 4 + j) * 1536 + gte * 512 + d]);
    } else {
#pragma unroll
      for (int j = 0; j < 4; ++j) {
        gir[0][j] = gr_[j] + bi0; gir[1][j] = gz_[j] + bi1; gir[2][j] = gn_[j] + bi2;
      }
    }

    // ---- gather own h(t-1), stage to hs ----
    gather_poll(ownp + (size_t)((t - 1) & 1) * 4096, (u32)(t - 1), w, lane, hs);
    __syncthreads();

    // ---- h matvec ----
    f32x4 ar = {0.f, 0.f, 0.f, 0.f}, az = ar, an = ar;
#pragma unroll
    for (int kc = 0; kc < 16; ++kc) {
      int cb = kc * 64 + kg * 16;
      short8 a = *(const short8*)((const char*)hs + col * 1024 + (cb ^ ((col & 7) << 4)));
      ar = __builtin_amdgcn_mfma_f32_16x16x32_bf16(a, wh0[kc], ar, 0, 0, 0);
      az = __builtin_amdgcn_mfma_f32_16x16x32_bf16(a, wh1[kc], az, 0, 0, 0);
      an = __builtin_amdgcn_mfma_f32_16x16x32_bf16(a, wh2[kc], an, 0, 0, 0);
    }
    // ---- gates ----
    u32 po[4];
#pragma unroll
    for (int j = 0; j < 4; ++j) {
      float rg = 1.f / (1.f + expf(-(gir[0][j] + ar[j] + bh0)));
      float zg = 1.f / (1.f + expf(-(gir[1][j] + az[j] + bh1)));
      float ng = tanhf(gir[2][j] + rg * (an[j] + bh2));
      float hn = (1.f - zg) * ng + zg * hprev[j];
      hprev[j] = hn;
      po[j] = (u32)f2bf(hn);
    }

    // ---- publish h(t): own plane (+ x-ring for l<2, xout for l==2) ----
    {
      const u32 tg = (u32)t << 16;
      u32 pn[4];
#pragma unroll
      for (int j = 0; j < 4; ++j) pn[j] = (u32)__shfl_xor((int)po[j], 1);
      int j0 = ev ? 0 : 2;
      u64 wd[2]; int wi_[2];
#pragma unroll
      for (int jj = 0; jj < 2; ++jj) {
        int j = j0 + jj;
        u32 lo = (ev ? po[j] : pn[j]) | tg;
        u32 hi = (ev ? pn[j] : po[j]) | tg;
        int row = kg * 4 + j;
        wd[jj] = (u64)lo | ((u64)hi << 32);
        wi_[jj] = row * 256 + blk * 32 + w * 8 + (col >> 1);
      }
      u64* op = ownp + (size_t)(t & 1) * 4096;
#pragma unroll
      for (int jj = 0; jj < 2; ++jj)
        __hip_atomic_store(op + wi_[jj], wd[jj], __ATOMIC_RELAXED, __HIP_MEMORY_SCOPE_AGENT);

      if (l < 2) {
        if (t > 8) {  // back-pressure: consumer must have finished t-8
          u32 need = (u32)(t - 8);
          u32 ctag = (u32)(bpv >> 16) & 0xFFFFu;
          while (ctag < need) {
            __builtin_amdgcn_s_sleep(8);
            bpv = __hip_atomic_load(consp + (size_t)((t - 8) & 1) * 4096 + blk * 32,
                                    __ATOMIC_RELAXED, __HIP_MEMORY_SCOPE_AGENT);
            ctag = (u32)(bpv >> 16) & 0xFFFFu;
          }
        }
        u64* xp = dnx + (size_t)(t & 7) * 4096;
#pragma unroll
        for (int jj = 0; jj < 2; ++jj)
          __hip_atomic_store(xp + wi_[jj], wd[jj], __ATOMIC_RELAXED, __HIP_MEMORY_SCOPE_AGENT);
        // prefetch bp word for next step's publish
        if (t >= 8)
          bpv = __hip_atomic_load(consp + (size_t)((t - 7) & 1) * 4096 + blk * 32,
                                  __ATOMIC_RELAXED, __HIP_MEMORY_SCOPE_AGENT);
      } else {
        // xout: quad-pack 4 cols per u64
        u32 pr[4], qr[4];
#pragma unroll
        for (int j = 0; j < 4; ++j) {
          pr[j] = ev ? (po[j] | (pn[j] << 16)) : (pn[j] | (po[j] << 16));
          qr[j] = (u32)__shfl_xor((int)pr[j], 2);
        }
        int jx = col & 3;
        u64 raw = ((col & 2) == 0) ? ((u64)pr[jx] | ((u64)qr[jx] << 32))
                                   : ((u64)qr[jx] | ((u64)pr[jx] << 32));
        int row = kg * 4 + jx;
        *(u64*)(xout + ((size_t)(t - 1) * 16 + row) * 512 + blk * 64 + w * 16 + (col & ~3)) = raw;
      }
    }

    // ---- tail (l>0): gather x(t+1), compute gi(t+1) in the shadow ----
    if (l > 0 && t < 1024) {
      gather_poll(upx + (size_t)((t + 1) & 7) * 4096, (u32)(t + 1), w, lane, hs2);
      __syncthreads();
      gr_ = (f32x4){0.f, 0.f, 0.f, 0.f}; gz_ = gr_; gn_ = gr_;
#pragma unroll
      for (int kc = 0; kc < 16; ++kc) {
        int cb = kc * 64 + kg * 16;
        short8 a = *(const short8*)((const char*)hs2 + col * 1024 + (cb ^ ((col & 7) << 4)));
        gr_ = __builtin_amdgcn_mfma_f32_16x16x32_bf16(a, wi0[kc], gr_, 0, 0, 0);
        gz_ = __builtin_amdgcn_mfma_f32_16x16x32_bf16(a, wi1[kc], gz_, 0, 0, 0);
        gn_ = __builtin_amdgcn_mfma_f32_16x16x32_bf16(a, wi2[kc], gn_, 0, 0, 0);
      }
    }
    __syncthreads();   // protect hs/hs2 reuse next iteration
  }
}

// ---------------- host ----------------
extern "C" void kernel_launch(void* const* d_in, const int* in_sizes, int n_in,
                              void* d_out, int out_size, void* d_ws, size_t ws_size,
                              hipStream_t stream) {
  const float* inp = (const float*)d_in[0];
  const float* h0  = (const float*)d_in[1];
  const float* wih = (const float*)d_in[2];
  const float* whh = (const float*)d_in[3];
  const float* bih = (const float*)d_in[4];
  const float* bhh = (const float*)d_in[5];
  const float* g0  = (const float*)d_in[6];
  const float* be0 = (const float*)d_in[7];
  const float* g1  = (const float*)d_in[8];
  const float* be1 = (const float*)d_in[9];
  const float* w1  = (const float*)d_in[10];
  const float* b1  = (const float*)d_in[11];
  const float* w2  = (const float*)d_in[12];
  const float* b2  = (const float*)d_in[13];
  float* out = (float*)d_out;

  char* p = (char*)d_ws;
  auto alloc = [&](size_t bytes) {
    char* r = p;
    p += (bytes + 255) & ~(size_t)255;
    return r;
  };
  u16* xa    = (u16*)alloc(16384ull * 512 * 2);
  u16* xb    = (u16*)alloc(16384ull * 512 * 2);
  u16* gib   = (u16*)alloc(16384ull * 1536 * 2);
  u16* mid   = (u16*)alloc(16384ull * 2048 * 2);
  float* outf = (float*)alloc(16384ull * 512 * 4);
  u16* wihb  = (u16*)alloc(3ull * 1536 * 512 * 2);
  u16* whhb  = (u16*)alloc(3ull * 1536 * 512 * 2);
  u16* w1t   = (u16*)alloc(2048ull * 512 * 2);
  u16* w2t   = (u16*)alloc(512ull * 2048 * 2);
  u64* hbuf  = (u64*)alloc(3ull * 2 * 4096 * 8);   // per-layer tagged h planes
  u64* xr    = (u64*)alloc(2ull * 8 * 4096 * 8);   // cross-layer x rings (depth 8)

  hipMemsetAsync(hbuf, 0, 3ull * 2 * 4096 * 8, stream);   // tags -> 0 (replay-safe)
  hipMemsetAsync(xr,   0, 2ull * 8 * 4096 * 8, stream);
  cast_kernel<<<(3 * 1536 * 512) / 1024, 256, 0, stream>>>(wih, wihb, 3 * 1536 * 512);
  cast_kernel<<<(3 * 1536 * 512) / 1024, 256, 0, stream>>>(whh, whhb, 3 * 1536 * 512);
  hprep_kernel<<<3, 256, 0, stream>>>(h0, hbuf);
  tcast_kernel<<<dim3(2048 / 32, 512 / 32), dim3(32, 8), 0, stream>>>(w1, w1t, 512, 2048);
  tcast_kernel<<<dim3(512 / 32, 2048 / 32), dim3(32, 8), 0, stream>>>(w2, w2t, 2048, 512);
  ln0_kernel<<<16384, 256, 0, stream>>>(inp, g0, be0, xa);

  // gi GEMM for layer 0 only
  gemm_bt<0><<<dim3(12, 128), 256, 0, stream>>>(xa, wihb, (void*)gib, bih, nullptr,
                                                16384, 1536, 512);
  // fused 3-layer pipelined recurrence
  rec3_kernel<<<24, 256, 0, stream>>>(gib, whhb, wihb, bih, bhh, h0, hbuf, xr, xb);

  resid_ln1_kernel<<<16384, 256, 0, stream>>>(inp, xb, g1, be1, outf, xa);
  gemm_bt<1><<<dim3(16, 128), 256, 0, stream>>>(xa, w1t, (void*)mid, b1, nullptr,
                                                16384, 2048, 512);
  gemm_bt<2><<<dim3(4, 128), 256, 0, stream>>>(mid, w2t, (void*)out, b2, outf,
                                               16384, 512, 2048);
}

// Round 5
// 4960.391 us; speedup vs baseline: 3.9022x; 1.5548x over previous
//
#include <hip/hip_runtime.h>
#include <hip/hip_bf16.h>

typedef unsigned short u16;
typedef unsigned int   u32;
typedef unsigned long long u64;
typedef __attribute__((ext_vector_type(8))) short short8;
typedef __attribute__((ext_vector_type(4))) float f32x4;

__device__ __forceinline__ float bf2f(u16 u) {
  union { u32 i; float f; } v; v.i = ((u32)u) << 16; return v.f;
}
__device__ __forceinline__ u16 f2bf(float f) {
  union { float f; u32 i; } v; v.f = f;
  return (u16)((v.i + 0x7FFFu + ((v.i >> 16) & 1u)) >> 16);
}

typedef const __attribute__((address_space(1))) u32* gas_t;
typedef __attribute__((address_space(3)))       u32* las_t;
__device__ __forceinline__ void gld16(const void* g, void* l) {
  __builtin_amdgcn_global_load_lds((gas_t)g, (las_t)l, 16, 0, 0);
}

// ---------------- elementwise prep ----------------
__global__ __launch_bounds__(256) void cast_kernel(const float* __restrict__ src,
                                                   u16* __restrict__ dst, int n) {
  int i = (blockIdx.x * 256 + threadIdx.x) * 4;
  if (i >= n) return;
  float4 v = *(const float4*)(src + i);
  uint2 o;
  o.x = (u32)f2bf(v.x) | ((u32)f2bf(v.y) << 16);
  o.y = (u32)f2bf(v.z) | ((u32)f2bf(v.w) << 16);
  *(uint2*)(dst + i) = o;
}

// dst[c][r] = bf16(src[r][c]);  R,C multiples of 32
__global__ __launch_bounds__(256) void tcast_kernel(const float* __restrict__ src,
                                                    u16* __restrict__ dst, int R, int C) {
  __shared__ u16 tile[32][33];
  int c0 = blockIdx.x * 32, r0 = blockIdx.y * 32;
  for (int dy = threadIdx.y; dy < 32; dy += 8)
    tile[dy][threadIdx.x] = f2bf(src[(size_t)(r0 + dy) * C + c0 + threadIdx.x]);
  __syncthreads();
  for (int dy = threadIdx.y; dy < 32; dy += 8)
    dst[(size_t)(c0 + dy) * R + r0 + threadIdx.x] = tile[threadIdx.x][dy];
}

// h0 (f32 [16][512] per layer) -> tagged u64 plane (parity 0), tag = 0
__global__ __launch_bounds__(256) void hprep_kernel(const float* __restrict__ h0,
                                                    u64* __restrict__ hbuf) {
  int l = blockIdx.x;
  const float* h = h0 + l * 8192;
  u64* buf = hbuf + (size_t)l * 2 * 4096;   // parity-0 plane
  for (int idx = threadIdx.x; idx < 4096; idx += 256) {
    int row = idx >> 8, wl = idx & 255;
    int d0 = wl * 2;
    u64 p0 = f2bf(h[row * 512 + d0]);
    u64 p1 = f2bf(h[row * 512 + d0 + 1]);
    buf[idx] = p0 | (p1 << 32);            // tags = 0
  }
}

// LN over D=512, input [B][S][D] f32, output time-major [S][B][D] bf16
__global__ __launch_bounds__(256) void ln0_kernel(const float* __restrict__ in,
                                                  const float* __restrict__ g,
                                                  const float* __restrict__ be,
                                                  u16* __restrict__ xout) {
  int m = blockIdx.x;            // b*1024 + s
  int b = m >> 10, s = m & 1023;
  int i = threadIdx.x * 2;
  float2 v = *(const float2*)(in + (size_t)m * 512 + i);
  float sum = v.x + v.y, sq = v.x * v.x + v.y * v.y;
  for (int o = 32; o > 0; o >>= 1) { sum += __shfl_down(sum, o); sq += __shfl_down(sq, o); }
  __shared__ float red[10];
  int w = threadIdx.x >> 6, lane = threadIdx.x & 63;
  if (!lane) { red[w] = sum; red[w + 4] = sq; }
  __syncthreads();
  if (threadIdx.x == 0) {
    sum = red[0] + red[1] + red[2] + red[3];
    sq  = red[4] + red[5] + red[6] + red[7];
    float mu = sum * (1.f / 512.f), var = sq * (1.f / 512.f) - mu * mu;
    red[8] = mu; red[9] = rsqrtf(var + 1e-5f);
  }
  __syncthreads();
  float mu = red[8], rs = red[9];
  u32 o0 = (u32)f2bf((v.x - mu) * rs * g[i] + be[i]) |
           ((u32)f2bf((v.y - mu) * rs * g[i + 1] + be[i + 1]) << 16);
  *(u32*)(xout + (size_t)(s * 16 + b) * 512 + i) = o0;
}

// out = inputs + h(time-major);  y = bf16(LN(out))
__global__ __launch_bounds__(256) void resid_ln1_kernel(const float* __restrict__ in,
                                                        const u16* __restrict__ hrec,
                                                        const float* __restrict__ g,
                                                        const float* __restrict__ be,
                                                        float* __restrict__ outf,
                                                        u16* __restrict__ y) {
  int m = blockIdx.x;            // b*1024 + s
  int b = m >> 10, s = m & 1023;
  int i = threadIdx.x * 2;
  float2 v = *(const float2*)(in + (size_t)m * 512 + i);
  u32 hu = *(const u32*)(hrec + (size_t)(s * 16 + b) * 512 + i);
  v.x += bf2f((u16)(hu & 0xffff));
  v.y += bf2f((u16)(hu >> 16));
  *(float2*)(outf + (size_t)m * 512 + i) = v;
  float sum = v.x + v.y, sq = v.x * v.x + v.y * v.y;
  for (int o = 32; o > 0; o >>= 1) { sum += __shfl_down(sum, o); sq += __shfl_down(sq, o); }
  __shared__ float red[10];
  int w = threadIdx.x >> 6, lane = threadIdx.x & 63;
  if (!lane) { red[w] = sum; red[w + 4] = sq; }
  __syncthreads();
  if (threadIdx.x == 0) {
    sum = red[0] + red[1] + red[2] + red[3];
    sq  = red[4] + red[5] + red[6] + red[7];
    float mu = sum * (1.f / 512.f), var = sq * (1.f / 512.f) - mu * mu;
    red[8] = mu; red[9] = rsqrtf(var + 1e-5f);
  }
  __syncthreads();
  float mu = red[8], rs = red[9];
  u32 o0 = (u32)f2bf((v.x - mu) * rs * g[i] + be[i]) |
           ((u32)f2bf((v.y - mu) * rs * g[i + 1] + be[i + 1]) << 16);
  *(u32*)(y + (size_t)m * 512 + i) = o0;
}

// ---------------- bf16 MFMA GEMM: C[M][N] = A[M][K] * Bt[N][K]^T ----------------
template <int EPI>
__global__ __launch_bounds__(256, 2)
void gemm_bt(const u16* __restrict__ A, const u16* __restrict__ Bt,
             void* __restrict__ Out, const float* __restrict__ bias,
             const float* __restrict__ resid, int M, int N, int K) {
  __shared__ u16 As[128 * 64];
  __shared__ u16 Bs[128 * 64];
  const int bn = blockIdx.x, bm = blockIdx.y;
  const int tid = threadIdx.x;
  const int w = tid >> 6, lane = tid & 63;
  const int wr = w >> 1, wc = w & 1;
  const int col = lane & 15, kg = lane >> 4;
  const int l8 = lane >> 3, l7 = lane & 7;
  f32x4 acc[4][4];
#pragma unroll
  for (int i = 0; i < 4; ++i)
#pragma unroll
    for (int j = 0; j < 4; ++j) acc[i][j] = (f32x4){0.f, 0.f, 0.f, 0.f};

  for (int k0 = 0; k0 < K; k0 += 64) {
    __syncthreads();
#pragma unroll
    for (int i = 0; i < 4; ++i) {
      int q = w * 4 + i;
      int row = q * 8 + l8;
      int cswz = (l7 * 16) ^ ((row & 7) << 4);
      gld16((const char*)A + ((size_t)(bm * 128 + row) * K + k0) * 2 + cswz,
            (char*)As + q * 1024);
      gld16((const char*)Bt + ((size_t)(bn * 128 + row) * K + k0) * 2 + cswz,
            (char*)Bs + q * 1024);
    }
    asm volatile("s_waitcnt vmcnt(0)" ::: "memory");
    __syncthreads();
#pragma unroll
    for (int kc = 0; kc < 2; ++kc) {
      short8 af[4], bfr[4];
      int cb = kc * 64 + kg * 16;
#pragma unroll
      for (int mi = 0; mi < 4; ++mi) {
        int r = wr * 64 + mi * 16 + col;
        af[mi] = *(const short8*)((const char*)As + r * 128 + (cb ^ ((r & 7) << 4)));
      }
#pragma unroll
      for (int ni = 0; ni < 4; ++ni) {
        int r = wc * 64 + ni * 16 + col;
        bfr[ni] = *(const short8*)((const char*)Bs + r * 128 + (cb ^ ((r & 7) << 4)));
      }
#pragma unroll
      for (int mi = 0; mi < 4; ++mi)
#pragma unroll
        for (int ni = 0; ni < 4; ++ni)
          acc[mi][ni] = __builtin_amdgcn_mfma_f32_16x16x32_bf16(af[mi], bfr[ni], acc[mi][ni], 0, 0, 0);
    }
  }
#pragma unroll
  for (int ni = 0; ni < 4; ++ni) {
    int gn = bn * 128 + wc * 64 + ni * 16 + col;
    float bv = bias ? bias[gn] : 0.f;
#pragma unroll
    for (int mi = 0; mi < 4; ++mi) {
      int gmb = bm * 128 + wr * 64 + mi * 16 + kg * 4;
#pragma unroll
      for (int j = 0; j < 4; ++j) {
        float v = acc[mi][ni][j] + bv;
        size_t idx = (size_t)(gmb + j) * N + gn;
        if (EPI == 0) {
          ((u16*)Out)[idx] = f2bf(v);
        } else if (EPI == 1) {
          float gel = 0.5f * v * (1.f + erff(v * 0.7071067811865476f));
          ((u16*)Out)[idx] = f2bf(gel);
        } else {
          ((float*)Out)[idx] = v + resid[idx];
        }
      }
    }
  }
}

// ---------------- gather/poll helper: tagged u64 plane -> swizzled LDS ----------------
__device__ __forceinline__ void gather_poll(const u64* __restrict__ plane, u32 want,
                                            int w, int lane, u16* __restrict__ lds) {
  const u64 TM = 0xFFFF0000FFFF0000ULL;
  const u64 ex = ((u64)want << 16) | ((u64)want << 48);
  u64 v[16];
#pragma unroll
  for (int r = 0; r < 4; ++r)
#pragma unroll
    for (int q = 0; q < 4; ++q)
      v[r * 4 + q] = __hip_atomic_load(plane + (size_t)(w * 4 + r) * 256 + lane * 4 + q,
                                       __ATOMIC_RELAXED, __HIP_MEMORY_SCOPE_AGENT);
  for (;;) {
    bool ok = true;
#pragma unroll
    for (int i = 0; i < 16; ++i) ok &= ((v[i] ^ ex) & TM) == 0;
    if (ok) break;
    __builtin_amdgcn_s_sleep(1);
#pragma unroll
    for (int i = 0; i < 16; ++i)
      if (((v[i] ^ ex) & TM) != 0)
        v[i] = __hip_atomic_load(plane + (size_t)(w * 4 + (i >> 2)) * 256 + lane * 4 + (i & 3),
                                 __ATOMIC_RELAXED, __HIP_MEMORY_SCOPE_AGENT);
  }
#pragma unroll
  for (int r = 0; r < 4; ++r) {
    int row = w * 4 + r;
    uint4 pk;
    pk.x = ((u32)v[r * 4 + 0] & 0xFFFFu) | ((u32)(v[r * 4 + 0] >> 32) << 16);
    pk.y = ((u32)v[r * 4 + 1] & 0xFFFFu) | ((u32)(v[r * 4 + 1] >> 32) << 16);
    pk.z = ((u32)v[r * 4 + 2] & 0xFFFFu) | ((u32)(v[r * 4 + 2] >> 32) << 16);
    pk.w = ((u32)v[r * 4 + 3] & 0xFFFFu) | ((u32)(v[r * 4 + 3] >> 32) << 16);
    *(uint4*)((char*)lds + row * 1024 + ((lane * 16) ^ ((row & 7) << 4))) = pk;
  }
}

// ---------------- fused 3-layer GRU, role-split + XCD-colocated ----------------
// Grid 64 blocks; res = idx&7 (de-facto XCD under round-robin), grp = idx>>3.
//  res 0,1,2: h-block, layer l=res, slice blk=grp  -> layer's 8 h-blocks share one XCD
//  res 3,4  : gi-block, layer l=res-2, slice k=grp (holds W_ih only)
//  res 5,6,7: exit.
// h-block loop = round-3 structure; gi arrives via tagged gi-plane (depth-4 ring),
// computed one pipeline-stage earlier by the gi-block. All waits monotone+acyclic.
__global__ __launch_bounds__(256, 1)
void rec3_kernel(const u16* __restrict__ gib, const u16* __restrict__ whhb,
                 const u16* __restrict__ wihb, const float* __restrict__ bih,
                 const float* __restrict__ bhh, const float* __restrict__ h0,
                 u64* __restrict__ hpl, u64* __restrict__ xr,
                 u64* __restrict__ gip, u16* __restrict__ xout) {
  const int res = blockIdx.x & 7, grp = blockIdx.x >> 3;
  if (res > 4) return;
  __shared__ u16 hs[16 * 512];
  const int tid = threadIdx.x;
  const int w = tid >> 6, lane = tid & 63;
  const int col = lane & 15, kg = lane >> 4;
  const u64 TM = 0xFFFF0000FFFF0000ULL;

  if (res >= 3) {
    // ================= gi-block: layer l = res-2, slice k = grp =================
    const int l = res - 2, k = grp;
    const int d = k * 64 + w * 16 + col;
    const u16* wih = wihb + (size_t)l * 1536 * 512;
    short8 wi0[16], wi1[16], wi2[16];
    {
      const u16* r0 = wih + (size_t)(0 * 512 + d) * 512;
      const u16* r1 = wih + (size_t)(1 * 512 + d) * 512;
      const u16* r2 = wih + (size_t)(2 * 512 + d) * 512;
#pragma unroll
      for (int kc = 0; kc < 16; ++kc) {
        wi0[kc] = *(const short8*)(r0 + kc * 32 + kg * 8);
        wi1[kc] = *(const short8*)(r1 + kc * 32 + kg * 8);
        wi2[kc] = *(const short8*)(r2 + kc * 32 + kg * 8);
      }
    }
    const float bi0 = bih[l * 1536 + d], bi1 = bih[l * 1536 + 512 + d],
                bi2 = bih[l * 1536 + 1024 + d];
    const u64* upx = xr + (size_t)(l - 1) * 8 * 4096;
    u64* gout = gip + (size_t)(l - 1) * 4 * 12288;
    const u64* hpc = hpl + (size_t)l * 2 * 4096;   // consumer progress (layer-l h-plane)
    u64 bpv = 0;

    for (int t = 1; t <= 1024; ++t) {
      gather_poll(upx + (size_t)(t & 7) * 4096, (u32)t, w, lane, hs);
      __syncthreads();
      f32x4 ar = {0.f, 0.f, 0.f, 0.f}, az = ar, an = ar;
#pragma unroll
      for (int kc = 0; kc < 16; ++kc) {
        int cb = kc * 64 + kg * 16;
        short8 a = *(const short8*)((const char*)hs + col * 1024 + (cb ^ ((col & 7) << 4)));
        ar = __builtin_amdgcn_mfma_f32_16x16x32_bf16(a, wi0[kc], ar, 0, 0, 0);
        az = __builtin_amdgcn_mfma_f32_16x16x32_bf16(a, wi1[kc], az, 0, 0, 0);
        an = __builtin_amdgcn_mfma_f32_16x16x32_bf16(a, wi2[kc], an, 0, 0, 0);
      }
      // back-pressure: overwriting gi(t-4) in slot t&3 needs h_l >= t-4
      if (t > 4) {
        u32 need = (u32)(t - 4);
        u32 ctag = (u32)(bpv >> 16) & 0xFFFFu;
        while (ctag < need) {
          __builtin_amdgcn_s_sleep(8);
          bpv = __hip_atomic_load(hpc + (size_t)(need & 1) * 4096 + k * 32,
                                  __ATOMIC_RELAXED, __HIP_MEMORY_SCOPE_AGENT);
          ctag = (u32)(bpv >> 16) & 0xFFFFu;
        }
      }
      // publish gi(t)+bias, tagged
      {
        const u32 tgl = (u32)t << 16;
        u64* slot = gout + (size_t)(t & 3) * 12288 + (size_t)k * 1536;
#pragma unroll
        for (int g = 0; g < 3; ++g) {
          f32x4 a = (g == 0) ? ar : ((g == 1) ? az : an);
          float bg = (g == 0) ? bi0 : ((g == 1) ? bi1 : bi2);
#pragma unroll
          for (int jh = 0; jh < 2; ++jh) {
            u32 lo = (u32)f2bf(a[2 * jh] + bg) | tgl;
            u32 hi = (u32)f2bf(a[2 * jh + 1] + bg) | tgl;
            __hip_atomic_store(slot + (size_t)(g * 64 + w * 16 + col) * 8 + kg * 2 + jh,
                               (u64)lo | ((u64)hi << 32),
                               __ATOMIC_RELAXED, __HIP_MEMORY_SCOPE_AGENT);
          }
        }
      }
      // prefetch consumer progress for next step (need' = t-3)
      if (t >= 4)
        bpv = __hip_atomic_load(hpc + (size_t)((t - 3) & 1) * 4096 + k * 32,
                                __ATOMIC_RELAXED, __HIP_MEMORY_SCOPE_AGENT);
      __syncthreads();   // hs reuse
    }
    return;
  }

  // ================= h-block: layer l = res, slice blk = grp =================
  const int l = res, blk = grp;
  const int d = blk * 64 + w * 16 + col;
  const u16* whh = whhb + (size_t)l * 1536 * 512;
  short8 wh0[16], wh1[16], wh2[16];
  {
    const u16* r0 = whh + (size_t)(0 * 512 + d) * 512;
    const u16* r1 = whh + (size_t)(1 * 512 + d) * 512;
    const u16* r2 = whh + (size_t)(2 * 512 + d) * 512;
#pragma unroll
    for (int kc = 0; kc < 16; ++kc) {
      wh0[kc] = *(const short8*)(r0 + kc * 32 + kg * 8);
      wh1[kc] = *(const short8*)(r1 + kc * 32 + kg * 8);
      wh2[kc] = *(const short8*)(r2 + kc * 32 + kg * 8);
    }
  }
  const float bh0 = bhh[l * 1536 + d], bh1 = bhh[l * 1536 + 512 + d],
              bh2 = bhh[l * 1536 + 1024 + d];
  float hprev[4];
#pragma unroll
  for (int j = 0; j < 4; ++j) hprev[j] = h0[l * 8192 + (kg * 4 + j) * 512 + d];

  u64* ownp = hpl + (size_t)l * 2 * 4096;
  u64* dnx = xr + (size_t)l * 8 * 4096;                    // l<2
  const u64* gin = gip + (size_t)(l - 1) * 4 * 12288;      // l>0
  const u64* gchk = gip + (size_t)l * 4 * 12288;           // l<2: layer l+1 gi progress
  const bool ev = !(col & 1);
  u64 bp8 = 0;

  for (int t = 1; t <= 1024; ++t) {
    float gir[3][4];
    u64 gv[6];
    if (l == 0) {
#pragma unroll
      for (int gte = 0; gte < 3; ++gte)
#pragma unroll
        for (int j = 0; j < 4; ++j)
          gir[gte][j] = bf2f(gib[((size_t)(t - 1) * 16 + kg * 4 + j) * 1536 + gte * 512 + d]);
    } else {
      const u64* gs = gin + (size_t)(t & 3) * 12288 + (size_t)blk * 1536;
#pragma unroll
      for (int g = 0; g < 3; ++g)
#pragma unroll
        for (int jh = 0; jh < 2; ++jh)
          gv[g * 2 + jh] = __hip_atomic_load(gs + (size_t)(g * 64 + w * 16 + col) * 8 + kg * 2 + jh,
                                             __ATOMIC_RELAXED, __HIP_MEMORY_SCOPE_AGENT);
    }

    gather_poll(ownp + (size_t)((t - 1) & 1) * 4096, (u32)(t - 1), w, lane, hs);

    if (l > 0) {
      const u64 exg = ((u64)t << 16) | ((u64)t << 48);
      const u64* gs = gin + (size_t)(t & 3) * 12288 + (size_t)blk * 1536;
      for (;;) {
        bool ok = true;
#pragma unroll
        for (int i = 0; i < 6; ++i) ok &= ((gv[i] ^ exg) & TM) == 0;
        if (ok) break;
        __builtin_amdgcn_s_sleep(1);
#pragma unroll
        for (int g = 0; g < 3; ++g)
#pragma unroll
          for (int jh = 0; jh < 2; ++jh)
            if (((gv[g * 2 + jh] ^ exg) & TM) != 0)
              gv[g * 2 + jh] = __hip_atomic_load(gs + (size_t)(g * 64 + w * 16 + col) * 8 + kg * 2 + jh,
                                                 __ATOMIC_RELAXED, __HIP_MEMORY_SCOPE_AGENT);
      }
#pragma unroll
      for (int g = 0; g < 3; ++g)
#pragma unroll
        for (int jh = 0; jh < 2; ++jh) {
          gir[g][2 * jh]     = bf2f((u16)gv[g * 2 + jh]);
          gir[g][2 * jh + 1] = bf2f((u16)(gv[g * 2 + jh] >> 32));
        }
    }
    __syncthreads();

    // ---- h matvec ----
    f32x4 ar = {0.f, 0.f, 0.f, 0.f}, az = ar, an = ar;
#pragma unroll
    for (int kc = 0; kc < 16; ++kc) {
      int cb = kc * 64 + kg * 16;
      short8 a = *(const short8*)((const char*)hs + col * 1024 + (cb ^ ((col & 7) << 4)));
      ar = __builtin_amdgcn_mfma_f32_16x16x32_bf16(a, wh0[kc], ar, 0, 0, 0);
      az = __builtin_amdgcn_mfma_f32_16x16x32_bf16(a, wh1[kc], az, 0, 0, 0);
      an = __builtin_amdgcn_mfma_f32_16x16x32_bf16(a, wh2[kc], an, 0, 0, 0);
    }
    // ---- gates ----
    u32 po[4];
#pragma unroll
    for (int j = 0; j < 4; ++j) {
      float rg = 1.f / (1.f + expf(-(gir[0][j] + ar[j] + bh0)));
      float zg = 1.f / (1.f + expf(-(gir[1][j] + az[j] + bh1)));
      float ng = tanhf(gir[2][j] + rg * (an[j] + bh2));
      float hn = (1.f - zg) * ng + zg * hprev[j];
      hprev[j] = hn;
      po[j] = (u32)f2bf(hn);
    }

    // ---- publish h(t) ----
    {
      const u32 tg = (u32)t << 16;
      u32 pn[4];
#pragma unroll
      for (int j = 0; j < 4; ++j) pn[j] = (u32)__shfl_xor((int)po[j], 1);
      int j0 = ev ? 0 : 2;
      u64 wd[2]; int wi_[2];
#pragma unroll
      for (int jj = 0; jj < 2; ++jj) {
        int j = j0 + jj;
        u32 lo = (ev ? po[j] : pn[j]) | tg;
        u32 hi = (ev ? pn[j] : po[j]) | tg;
        int row = kg * 4 + j;
        wd[jj] = (u64)lo | ((u64)hi << 32);
        wi_[jj] = row * 256 + blk * 32 + w * 8 + (col >> 1);
      }
      u64* op = ownp + (size_t)(t & 1) * 4096;
#pragma unroll
      for (int jj = 0; jj < 2; ++jj)
        __hip_atomic_store(op + wi_[jj], wd[jj], __ATOMIC_RELAXED, __HIP_MEMORY_SCOPE_AGENT);

      if (l < 2) {
        // back-pressure: overwriting x(t-8) in ring slot t&7 needs gi_{l+1} >= t-8 (all slices)
        if (t > 8) {
          u32 need = (u32)(t - 8);
          for (;;) {
            u32 tg8 = (lane < 8) ? (u32)((bp8 >> 16) & 0xFFFFu) : 0xFFFFu;
            if (__all(tg8 >= need)) break;
            __builtin_amdgcn_s_sleep(8);
            if (lane < 8)
              bp8 = __hip_atomic_load(gchk + (size_t)(need & 3) * 12288 + (size_t)lane * 1536,
                                      __ATOMIC_RELAXED, __HIP_MEMORY_SCOPE_AGENT);
          }
        }
        u64* xp = dnx + (size_t)(t & 7) * 4096;
#pragma unroll
        for (int jj = 0; jj < 2; ++jj)
          __hip_atomic_store(xp + wi_[jj], wd[jj], __ATOMIC_RELAXED, __HIP_MEMORY_SCOPE_AGENT);
        // prefetch next step's progress words (need' = t-7)
        if (t >= 8 && lane < 8)
          bp8 = __hip_atomic_load(gchk + (size_t)((t - 7) & 3) * 12288 + (size_t)lane * 1536,
                                  __ATOMIC_RELAXED, __HIP_MEMORY_SCOPE_AGENT);
      } else {
        // xout: quad-pack 4 cols per u64
        u32 pr[4], qr[4];
#pragma unroll
        for (int j = 0; j < 4; ++j) {
          pr[j] = ev ? (po[j] | (pn[j] << 16)) : (pn[j] | (po[j] << 16));
          qr[j] = (u32)__shfl_xor((int)pr[j], 2);
        }
        int jx = col & 3;
        u64 raw = ((col & 2) == 0) ? ((u64)pr[jx] | ((u64)qr[jx] << 32))
                                   : ((u64)qr[jx] | ((u64)pr[jx] << 32));
        int row = kg * 4 + jx;
        *(u64*)(xout + ((size_t)(t - 1) * 16 + row) * 512 + blk * 64 + w * 16 + (col & ~3)) = raw;
      }
    }
    __syncthreads();   // protect hs reuse
  }
}

// ---------------- host ----------------
extern "C" void kernel_launch(void* const* d_in, const int* in_sizes, int n_in,
                              void* d_out, int out_size, void* d_ws, size_t ws_size,
                              hipStream_t stream) {
  const float* inp = (const float*)d_in[0];
  const float* h0  = (const float*)d_in[1];
  const float* wih = (const float*)d_in[2];
  const float* whh = (const float*)d_in[3];
  const float* bih = (const float*)d_in[4];
  const float* bhh = (const float*)d_in[5];
  const float* g0  = (const float*)d_in[6];
  const float* be0 = (const float*)d_in[7];
  const float* g1  = (const float*)d_in[8];
  const float* be1 = (const float*)d_in[9];
  const float* w1  = (const float*)d_in[10];
  const float* b1  = (const float*)d_in[11];
  const float* w2  = (const float*)d_in[12];
  const float* b2  = (const float*)d_in[13];
  float* out = (float*)d_out;

  char* p = (char*)d_ws;
  auto alloc = [&](size_t bytes) {
    char* r = p;
    p += (bytes + 255) & ~(size_t)255;
    return r;
  };
  u16* xa    = (u16*)alloc(16384ull * 512 * 2);
  u16* xb    = (u16*)alloc(16384ull * 512 * 2);
  u16* gib   = (u16*)alloc(16384ull * 1536 * 2);
  u16* mid   = (u16*)alloc(16384ull * 2048 * 2);
  float* outf = (float*)alloc(16384ull * 512 * 4);
  u16* wihb  = (u16*)alloc(3ull * 1536 * 512 * 2);
  u16* whhb  = (u16*)alloc(3ull * 1536 * 512 * 2);
  u16* w1t   = (u16*)alloc(2048ull * 512 * 2);
  u16* w2t   = (u16*)alloc(512ull * 2048 * 2);
  u64* hbuf  = (u64*)alloc(3ull * 2 * 4096 * 8);   // per-layer tagged h planes
  u64* xr    = (u64*)alloc(2ull * 8 * 4096 * 8);   // cross-layer x rings (depth 8)
  u64* gip   = (u64*)alloc(2ull * 4 * 12288 * 8);  // gi-planes (depth-4 ring)

  hipMemsetAsync(hbuf, 0, 3ull * 2 * 4096 * 8, stream);   // tags -> 0 (replay-safe)
  hipMemsetAsync(xr,   0, 2ull * 8 * 4096 * 8, stream);
  hipMemsetAsync(gip,  0, 2ull * 4 * 12288 * 8, stream);
  cast_kernel<<<(3 * 1536 * 512) / 1024, 256, 0, stream>>>(wih, wihb, 3 * 1536 * 512);
  cast_kernel<<<(3 * 1536 * 512) / 1024, 256, 0, stream>>>(whh, whhb, 3 * 1536 * 512);
  hprep_kernel<<<3, 256, 0, stream>>>(h0, hbuf);
  tcast_kernel<<<dim3(2048 / 32, 512 / 32), dim3(32, 8), 0, stream>>>(w1, w1t, 512, 2048);
  tcast_kernel<<<dim3(512 / 32, 2048 / 32), dim3(32, 8), 0, stream>>>(w2, w2t, 2048, 512);
  ln0_kernel<<<16384, 256, 0, stream>>>(inp, g0, be0, xa);

  // gi GEMM for layer 0 only
  gemm_bt<0><<<dim3(12, 128), 256, 0, stream>>>(xa, wihb, (void*)gib, bih, nullptr,
                                                16384, 1536, 512);
  // fused 3-layer pipelined recurrence (role-split, XCD-colocated)
  rec3_kernel<<<64, 256, 0, stream>>>(gib, whhb, wihb, bih, bhh, h0, hbuf, xr, gip, xb);

  resid_ln1_kernel<<<16384, 256, 0, stream>>>(inp, xb, g1, be1, outf, xa);
  gemm_bt<1><<<dim3(16, 128), 256, 0, stream>>>(xa, w1t, (void*)mid, b1, nullptr,
                                                16384, 2048, 512);
  gemm_bt<2><<<dim3(4, 128), 256, 0, stream>>>(mid, w2t, (void*)out, b2, outf,
                                               16384, 512, 2048);
}